// Round 6
// baseline (636.319 us; speedup 1.0000x reference)
//
#include <hip/hip_runtime.h>
#include <cstdint>

#define TT 300   // timesteps
#define TC 75    // TT/4
#define NBATCH 4

typedef float pf2 __attribute__((ext_vector_type(2)));   // packs to v_pk_fma_f32
typedef _Float16 h8t __attribute__((ext_vector_type(8)));  // 4 VGPRs = MFMA f16 A/B frag
typedef float f32x4 __attribute__((ext_vector_type(4)));   // MFMA C/D frag

// PSP + refractory IIR step, exact op order of the reference scan.
__device__ __forceinline__ void psp_step(float z, float& gp, float& hp, float& gr, float& hr, float& s_out) {
    hp = 0.90483741803595957f * (hp + gp);      // a_sr = exp(-1/10)
    gp = 0.90483741803595957f * gp + z;
    hr = 0.36787944117144233f * (hr + gr);      // a_rf = exp(-1)
    gr = 0.36787944117144233f * gr;
    float u = 0.27182818284590452f * hp + (-54.365636569180904f) * hr; // c_sr*hp + c_rf*hr
    float s = (u >= 10.0f) ? 1.0f : 0.0f;
    gr += s;
    s_out = s;
}

// Per-neuron scan over T, 12-step chunks, [p][300] layout (used for L0 and L6).
template <int R>
__global__ void k_scan_redp(const float* __restrict__ z, float* __restrict__ s,
                            int n_neur, int pstride) {
    int i = blockIdx.x * 64 + threadIdx.x;
    if (i >= n_neur) return;
    const float* zp = z + (size_t)i * TT;
    float* sp = s + (size_t)i * TT;
    float gp = 0.f, hp = 0.f, gr = 0.f, hr = 0.f;
#pragma unroll 1
    for (int c = 0; c < 25; ++c) {
        const float* p = zp + c * 12;
        float4 a0 = *(const float4*)(p);
        float4 a1 = *(const float4*)(p + 4);
        float4 a2 = *(const float4*)(p + 8);
#pragma unroll
        for (int r = 1; r < R; ++r) {
            const float* pr = p + (size_t)r * pstride;
            float4 b0 = *(const float4*)(pr);
            float4 b1 = *(const float4*)(pr + 4);
            float4 b2 = *(const float4*)(pr + 8);
            a0.x += b0.x; a0.y += b0.y; a0.z += b0.z; a0.w += b0.w;
            a1.x += b1.x; a1.y += b1.y; a1.z += b1.z; a1.w += b1.w;
            a2.x += b2.x; a2.y += b2.y; a2.z += b2.z; a2.w += b2.w;
        }
        float4 o0, o1, o2;
        psp_step(a0.x, gp, hp, gr, hr, o0.x);
        psp_step(a0.y, gp, hp, gr, hr, o0.y);
        psp_step(a0.z, gp, hp, gr, hr, o0.z);
        psp_step(a0.w, gp, hp, gr, hr, o0.w);
        psp_step(a1.x, gp, hp, gr, hr, o1.x);
        psp_step(a1.y, gp, hp, gr, hr, o1.y);
        psp_step(a1.z, gp, hp, gr, hr, o1.z);
        psp_step(a1.w, gp, hp, gr, hr, o1.w);
        psp_step(a2.x, gp, hp, gr, hr, o2.x);
        psp_step(a2.y, gp, hp, gr, hr, o2.y);
        psp_step(a2.z, gp, hp, gr, hr, o2.z);
        psp_step(a2.w, gp, hp, gr, hr, o2.w);
        float* q = sp + c * 12;
        *(float4*)(q) = o0;
        *(float4*)(q + 4) = o1;
        *(float4*)(q + 8) = o2;
    }
}

// Scan for L5 output: reads z5 in [tc][p][16] layout (p = n*4096 + f), writes f16
// spikes S16 [n][t][4096]. Wave reads are 64 lanes x 64B contiguous = 4KB segments.
__global__ void k_scan16_f16(const float* __restrict__ z, _Float16* __restrict__ s16) {
    int i = blockIdx.x * 64 + threadIdx.x;     // 16384 neurons, grid 256 x 64
    int n = i >> 12, f = i & 4095;
    const float* zp = z + (size_t)i * 16;
    _Float16* sp = s16 + ((size_t)n * TT) * 4096 + f;
    float gp = 0.f, hp = 0.f, gr = 0.f, hr = 0.f;
#define SC16_CHUNK(TCI, NTT) do {                                              \
    const float* pp = zp + (size_t)(TCI) * (16384 * 16);                       \
    float4 a0 = *(const float4*)(pp);                                          \
    float4 a1 = *(const float4*)(pp + 4);                                      \
    float4 a2 = *(const float4*)(pp + 8);                                      \
    float4 a3 = *(const float4*)(pp + 12);                                     \
    float zv[16] = {a0.x,a0.y,a0.z,a0.w,a1.x,a1.y,a1.z,a1.w,                   \
                    a2.x,a2.y,a2.z,a2.w,a3.x,a3.y,a3.z,a3.w};                  \
    _Pragma("unroll")                                                          \
    for (int tt = 0; tt < (NTT); ++tt) {                                       \
        float o;                                                               \
        psp_step(zv[tt], gp, hp, gr, hr, o);                                   \
        sp[(size_t)((TCI) * 16 + tt) * 4096] = (_Float16)o;                    \
    }                                                                          \
} while (0)
#pragma unroll 1
    for (int tcc = 0; tcc < 18; ++tcc) SC16_CHUNK(tcc, 16);
    SC16_CHUNK(18, 12);
#undef SC16_CHUNK
}

// Fused scan-pool-scan for L3 output: reads z3 [tc][p][16] (p = ((n*C+c)*H+y)*W+x),
// emits f16 spikes conv-native [n][c/8][y2][x2][t][8].
template <int C, int H2, int W2>
__global__ void __launch_bounds__(256) k_spsq16(const float* __restrict__ z,
                                                _Float16* __restrict__ s16) {
    constexpr int H = 2 * H2, W = 2 * W2;
    constexpr int NP = NBATCH * C * H * W;
    constexpr int C8 = C / 8;
    __shared__ _Float16 tile[16 * C];

    int i = blockIdx.x * 256 + threadIdx.x;    // grid exact: N*C*H2*W2*4 threads
    int q = i & 3;
    int p = i >> 2;
    int c  = p % C;
    int x2 = (p / C) % W2;
    int y2 = (p / (C * W2)) % H2;
    int n  = p / (C * W2 * H2);
    int dy = q >> 1, dx = q & 1;
    int pz = ((n * C + c) * H + 2 * y2 + dy) * W + 2 * x2 + dx;
    const float* zp = z + (size_t)pz * 16;

    int tid = threadIdx.x;
    int wt  = tid & 15;
    int wc8 = tid >> 4;
    int p0 = blockIdx.x * 64;                  // block's site (C-aligned p)
    int wx2 = (p0 / C) % W2;
    int wy2 = (p0 / (C * W2)) % H2;
    int wn  = p0 / (C * W2 * H2);
    _Float16* wbase = s16 + ((((size_t)(wn * C8 + wc8) * H2 + wy2) * W2 + wx2) * TT) * 8;

    float gp = 0.f, hp = 0.f, gr = 0.f, hr = 0.f;   // conv neuron IIR
    float Gp = 0.f, Hp = 0.f, Gr = 0.f, Hr = 0.f;   // pooled neuron IIR
#define SPSQ_CHUNK(TCI, NTT) do {                                              \
    const float* pp = zp + (size_t)(TCI) * (NP * 16);                          \
    float4 a0 = *(const float4*)(pp);                                          \
    float4 a1 = *(const float4*)(pp + 4);                                      \
    float4 a2 = *(const float4*)(pp + 8);                                      \
    float4 a3 = *(const float4*)(pp + 12);                                     \
    float zv[16] = {a0.x,a0.y,a0.z,a0.w,a1.x,a1.y,a1.z,a1.w,                   \
                    a2.x,a2.y,a2.z,a2.w,a3.x,a3.y,a3.z,a3.w};                  \
    float ov[16];                                                              \
    _Pragma("unroll")                                                          \
    for (int tt = 0; tt < (NTT); ++tt) {                                       \
        float sq;                                                              \
        psp_step(zv[tt], gp, hp, gr, hr, sq);                                  \
        float t1 = sq + __shfl_xor(sq, 1, 64);                                 \
        float pool = t1 + __shfl_xor(t1, 2, 64);                               \
        psp_step(11.0f * pool, Gp, Hp, Gr, Hr, ov[tt]);                        \
    }                                                                          \
    __syncthreads();                                                           \
    if (q == 0) {                                                              \
        _Pragma("unroll")                                                      \
        for (int tt = 0; tt < (NTT); ++tt)                                     \
            tile[tt * C + c] = (_Float16)ov[tt];                               \
    }                                                                          \
    __syncthreads();                                                           \
    if (tid < 16 * C8 && wt < (NTT)) {                                         \
        h8t v = *(const h8t*)(tile + wt * C + wc8 * 8);                        \
        *(h8t*)(wbase + (size_t)((TCI) * 16 + wt) * 8) = v;                    \
    }                                                                          \
} while (0)
#pragma unroll 1
    for (int tcc = 0; tcc < 18; ++tcc) SPSQ_CHUNK(tcc, 16);
    SPSQ_CHUNK(18, 12);
#undef SPSQ_CHUNK
}

// Pack 3x3 OIHW conv weights into MFMA A-fragments with f16 hi/lo split.
// Layout: [tap 9][kc CIN/32][ct COUT/16][ver 2][lane 64][j 8] halves.
__global__ void k_pack_wmfma(const float* __restrict__ w, _Float16* __restrict__ wm,
                             int CIN, int COUT, int total) {
    int i = blockIdx.x * 256 + threadIdx.x;
    if (i >= total) return;
    int lane = i & 63;
    int r = i >> 6;
    int ver = r & 1; r >>= 1;
    int KC = CIN >> 5, CT = COUT >> 4;
    int ct = r % CT; r /= CT;
    int kc = r % KC;
    int tap = r / KC;
    int ky = tap / 3, kx = tap % 3;
    int co  = ct * 16 + (lane & 15);
    int ci0 = kc * 32 + (lane >> 4) * 8;
    _Float16 out[8];
#pragma unroll
    for (int j = 0; j < 8; ++j) {
        float wf = w[((co * CIN + ci0 + j) * 3 + ky) * 3 + kx];
        _Float16 hi = (_Float16)wf;
        out[j] = ver ? (_Float16)((wf - (float)hi) * 4096.0f) : hi;
    }
    *(h8t*)(wm + (size_t)i * 8) = *(h8t*)out;
}

// Pack FC weights (COUT, FIN) row-major into MFMA A-fragments, hi/lo split.
__global__ void k_pack_wfc(const float* __restrict__ w, _Float16* __restrict__ wm,
                           int FIN, int COUT, int total) {
    int i = blockIdx.x * 256 + threadIdx.x;
    if (i >= total) return;
    int lane = i & 63;
    int r = i >> 6;
    int ver = r & 1; r >>= 1;
    int CT = COUT >> 4;
    int ct = r % CT;
    int kg = r / CT;
    int co = ct * 16 + (lane & 15);
    int f0 = kg * 32 + (lane >> 4) * 8;
    _Float16 out[8];
#pragma unroll
    for (int j = 0; j < 8; ++j) {
        float wf = w[(size_t)co * FIN + f0 + j];
        _Float16 hi = (_Float16)wf;
        out[j] = ver ? (_Float16)((wf - (float)hi) * 4096.0f) : hi;
    }
    *(h8t*)(wm + (size_t)i * 8) = *(h8t*)out;
}

// Pack L1 5x5 (32,2,5,5) weights into padded-K MFMA A-frags, hi/lo split.
// K = 96: k -> ky = k>>4, slot = k&15, kx = slot>>1, ci = slot&1; pad slots zero.
__global__ void k_pack_wl1(const float* __restrict__ w, _Float16* __restrict__ wm) {
    int i = blockIdx.x * 256 + threadIdx.x;
    if (i >= 768) return;
    int lane = i & 63;
    int r = i >> 6;
    int ver = r & 1;
    int ch = (r >> 1) & 1;
    int kc = r >> 2;
    int co = ch * 16 + (lane & 15);
    int k0 = kc * 32 + (lane >> 4) * 8;
    _Float16 out[8];
#pragma unroll
    for (int j = 0; j < 8; ++j) {
        int k = k0 + j;
        int ky = k >> 4, slot = k & 15, kx = slot >> 1, ci = slot & 1;
        float wf = (ky < 5 && kx < 5) ? w[((co * 2 + ci) * 5 + ky) * 5 + kx] : 0.f;
        _Float16 hif = (_Float16)wf;
        out[j] = ver ? (_Float16)((wf - (float)hif) * 4096.0f) : hif;
    }
    *(h8t*)(wm + (size_t)i * 8) = *(h8t*)out;
}

// 4x4 sum-pool * 11.0 over (N,2,128,128,T) -> z (N,2,32,32,T). Thread = (p, tc), tc fastest.
__global__ void k_pool4(const float* __restrict__ x, float* __restrict__ z) {
    int idx = blockIdx.x * 256 + threadIdx.x;
    if (idx >= NBATCH * 2 * 32 * 32 * TC) return;
    int tc = idx % TC;
    int p  = idx / TC;
    int w  = p % 32;
    int h  = (p / 32) % 32;
    int nc = p / (32 * 32);
    const float* base = x + (((size_t)nc * 128 + h * 4) * 128 + w * 4) * TT + tc * 4;
    float ax = 0.f, ay = 0.f, az = 0.f, aw = 0.f;
#pragma unroll
    for (int i = 0; i < 4; ++i)
#pragma unroll
        for (int j = 0; j < 4; ++j) {
            float4 v = *(const float4*)(base + ((size_t)i * 128 + j) * TT);
            ax += v.x; ay += v.y; az += v.z; aw += v.w;
        }
    float4 o; o.x = 11.0f * ax; o.y = 11.0f * ay; o.z = 11.0f * az; o.w = 11.0f * aw;
    *(float4*)(z + (size_t)p * TT + tc * 4) = o;
}

// Fused L1, single-wave blocks: 5x5 conv (2->32) MFMA + psp + 2x2 pool + psp.
// Block (64 thr, 1 wave) = (n, ch co-half, y2, x2): ONE pool site, 16 co, all 300 t.
// Grid 2048 -> ~16 blocks/CU co-resident (TLP hides the serial IIR + LDS latency;
// the old 512x256 version ran 2 blocks/CU, latency-bound at 131 us).
// Stage stride = 18 halves = 9 words (odd) -> B-frag dword reads are 2 lanes/bank
// (free); the old 40-half stride aliased to 8 banks (8-way, 6.5M conflict cycles).
__global__ void __launch_bounds__(64) k_l1_w64(const float* __restrict__ s0,
                                               const _Float16* __restrict__ wl1,
                                               _Float16* __restrict__ s2h) {
    constexpr int NT = 19;
    __shared__ _Float16 stage[7 * 16 * 18];   // [row7][t16][9 lx * 2 ci], 4032 B
    __shared__ float    trans[64 * 17];       // [neuron 64][16 t + pad]
    __shared__ _Float16 tile[16 * 16];        // [t][co]

    int bid = blockIdx.x;                     // grid 2048 = n4 * ch2 * y2_16 * x2_16
    int x2 = bid & 15;
    int y2 = (bid >> 4) & 15;
    int ch = (bid >> 8) & 1;
    int n  = bid >> 9;
    int tid = threadIdx.x;                    // == lane
    int tl = tid & 15;
    int hi = tid >> 4;

    // weights hoisted: [kc3][ver2] A-frags (lane-indexed, L2-broadcast)
    const h8t* wv4 = (const h8t*)wl1;
    h8t wfr[3][2];
#pragma unroll
    for (int kc = 0; kc < 3; ++kc) {
        wfr[kc][0] = wv4[((kc * 2 + ch) * 2 + 0) * 64 + tid];
        wfr[kc][1] = wv4[((kc * 2 + ch) * 2 + 1) * 64 + tid];
    }

    float gp = 0.f, hp = 0.f, gr = 0.f, hr = 0.f;   // conv neuron IIR
    float Gp = 0.f, Hp = 0.f, Gr = 0.f, Hr = 0.f;   // pooled neuron IIR

#pragma unroll 1
    for (int tc = 0; tc < NT; ++tc) {
        __syncthreads();
        // stage: 7 rows x 18 (lx,ci) x 16 t = 2016 f32 -> f16. t fastest (64B/16 lanes).
#pragma unroll
        for (int ii = 0; ii < 32; ++ii) {
            int i = tid + ii * 64;
            if (i < 2016) {
                int t    = i & 15;
                int lxci = (i >> 4) % 18;
                int row  = (i >> 4) / 18;
                int ci = lxci & 1, lx = lxci >> 1;
                int gx = x2 * 2 - 2 + lx;
                int gy = y2 * 2 - 2 + row;
                int tg = tc * 16 + t;
                float v = 0.f;
                if (gx >= 0 && gx < 32 && gy >= 0 && gy < 32 && tg < TT)
                    v = s0[(((size_t)(n * 2 + ci) * 32 + gy) * 32 + gx) * TT + tg];
                stage[(row * 16 + t) * 18 + lxci] = (_Float16)v;
            }
        }
        __syncthreads();
        // MFMA: acc[yy][xo][ver]; A k = kc*32+hi*8+j -> ky = 2kc+(hi>>1), slot = (hi&1)*8+j.
        // B[k][tl] = stage[(yy+2kc+(hi>>1))*16+tl][xo*2 + slot] (16 contiguous halves).
        f32x4 acc[2][2][2];
#pragma unroll
        for (int a = 0; a < 2; ++a)
#pragma unroll
            for (int b = 0; b < 2; ++b)
#pragma unroll
                for (int v = 0; v < 2; ++v) acc[a][b][v] = (f32x4){0.f, 0.f, 0.f, 0.f};
#pragma unroll
        for (int kc = 0; kc < 3; ++kc) {
#pragma unroll
            for (int yy = 0; yy < 2; ++yy) {
                int row = yy + 2 * kc + (hi >> 1);
#pragma unroll
                for (int xo = 0; xo < 2; ++xo) {
                    const uint32_t* lp = (const uint32_t*)(stage + (row * 16 + tl) * 18 + xo * 2 + (hi & 1) * 8);
                    union { uint32_t u[4]; h8t h; } bu;
                    bu.u[0] = lp[0]; bu.u[1] = lp[1]; bu.u[2] = lp[2]; bu.u[3] = lp[3];
                    acc[yy][xo][0] = __builtin_amdgcn_mfma_f32_16x16x32_f16(wfr[kc][0], bu.h, acc[yy][xo][0], 0, 0, 0);
                    acc[yy][xo][1] = __builtin_amdgcn_mfma_f32_16x16x32_f16(wfr[kc][1], bu.h, acc[yy][xo][1], 0, 0, 0);
                }
            }
        }
        // transpose -> trans[neuron][t]; neuron = co*4 + yy*2 + xo (co = hi*4+r).
#pragma unroll
        for (int yy = 0; yy < 2; ++yy)
#pragma unroll
            for (int xo = 0; xo < 2; ++xo)
#pragma unroll
                for (int r = 0; r < 4; ++r) {
                    float u = acc[yy][xo][0][r] + acc[yy][xo][1][r] * 2.44140625e-4f;
                    int neuron = (hi * 4 + r) * 4 + yy * 2 + xo;
                    trans[neuron * 17 + tl] = u;
                }
        __syncthreads();
        // scan: thread = conv neuron (bit0 = xo, bit1 = yy -> shfl quad pool exact).
        float zv[16];
#pragma unroll
        for (int t = 0; t < 16; ++t) zv[t] = trans[tid * 17 + t];
        int co_s = tid >> 2;
        int q = tid & 3;
#pragma unroll
        for (int t = 0; t < 16; ++t) {
            if (tc * 16 + t < TT) {
                float sq;
                psp_step(zv[t], gp, hp, gr, hr, sq);
                float t1 = sq + __shfl_xor(sq, 1, 64);
                float pool = t1 + __shfl_xor(t1, 2, 64);
                float ov;
                psp_step(11.0f * pool, Gp, Hp, Gr, Hr, ov);
                if (q == 0) tile[t * 16 + co_s] = (_Float16)ov;
            }
        }
        __syncthreads();
        // write: [n][cg8 4][y2][x2][t][8]; 32 threads, 16B each, 256B contiguous runs.
        if (tid < 32) {
            int t = tid & 15;
            int cg = tid >> 4;
            int tg = tc * 16 + t;
            if (tg < TT) {
                h8t v = *(const h8t*)(tile + t * 16 + cg * 8);
                *(h8t*)(s2h + ((((size_t)(n * 4 + ch * 2 + cg) * 16 + y2) * 16 + x2) * (size_t)TT + tg) * 8) = v;
            }
        }
    }
}

// MFMA 3x3 conv (pad 1). Input: f16 spikes [n][ci/8][y][x][t][8]. Output z in
// [tc][p][16] layout. Round-3 proven occupancy config: launch_bounds(256,2).
template <int CIN, int COUT, int H, int W, int YPB>
__global__ void __launch_bounds__(256, 2) k_conv_mfma(const _Float16* __restrict__ s16,
                                                      const _Float16* __restrict__ wm,
                                                      float* __restrict__ z) {
    constexpr int NT = 19;          // ceil(300/16)
    constexpr int KC = CIN / 32;
    constexpr int CH = CIN / 8;
    constexpr int XL = W + 2;
    constexpr int CT = COUT / 16;
    constexpr int XPW = W / 4;
    constexpr int ROWS = YPB + 2;
    constexpr int NP = NBATCH * COUT * H * W;
    __shared__ _Float16 lds[ROWS * XL * 16 * CIN];

    int bid = blockIdx.x;
    int tc = bid % NT;
    int yb = ((bid / NT) % (H / YPB)) * YPB;
    int n  = bid / (NT * (H / YPB));
    int tid = threadIdx.x;

    constexpr int TOT = ROWS * XL * CH * 16;
    for (int i = tid; i < TOT; i += 256) {
        int t   = i & 15;
        int c   = (i >> 4) % CH;
        int xc  = ((i >> 4) / CH) % XL;
        int row = ((i >> 4) / CH) / XL;
        int tg = tc * 16 + t;
        int xi = xc - 1;
        int yi = yb + row - 1;
        h8t v;
#pragma unroll
        for (int e = 0; e < 8; ++e) v[e] = (_Float16)0.0f;
        if (xi >= 0 && xi < W && yi >= 0 && yi < H && tg < TT)
            v = *(const h8t*)(s16 + ((((size_t)(n * CH + c) * H + yi) * W + xi) * TT + tg) * 8);
        int swz = (CIN == 32) ? ((t >> 1) & 3) : (t & 7);
        int off = ((row * XL + xc) * 16 + t) * CIN + ((c ^ swz) << 3);
        *(h8t*)(lds + off) = v;
    }
    __syncthreads();

    int lane = tid & 63;
    int wv   = tid >> 6;
    int tl   = lane & 15;
    int hi   = lane >> 4;
    const h8t* wmv = (const h8t*)wm;
    int swz = (CIN == 32) ? ((tl >> 1) & 3) : (tl & 7);

#pragma unroll
    for (int yy = 0; yy < YPB; ++yy) {
        f32x4 acc_h[XPW][CT], acc_l[XPW][CT];
#pragma unroll
        for (int a = 0; a < XPW; ++a)
#pragma unroll
            for (int b = 0; b < CT; ++b) {
                acc_h[a][b] = (f32x4){0.f, 0.f, 0.f, 0.f};
                acc_l[a][b] = (f32x4){0.f, 0.f, 0.f, 0.f};
            }
#pragma unroll
        for (int ky = 0; ky < 3; ++ky) {
#pragma unroll
            for (int kx = 0; kx < 3; ++kx) {
                int tap = ky * 3 + kx;
#pragma unroll
                for (int kc = 0; kc < KC; ++kc) {
                    h8t bf[XPW];
#pragma unroll
                    for (int xi = 0; xi < XPW; ++xi) {
                        int x = wv * XPW + xi;
                        int c = kc * 4 + hi;
                        int off = (((yy + ky) * XL + (x + kx)) * 16 + tl) * CIN + ((c ^ swz) << 3);
                        bf[xi] = *(const h8t*)(lds + off);
                    }
#pragma unroll
                    for (int ct = 0; ct < CT; ++ct) {
                        size_t wbase = ((size_t)(tap * KC + kc) * CT + ct) * 2;
                        h8t ah = wmv[(wbase + 0) * 64 + lane];
                        h8t al = wmv[(wbase + 1) * 64 + lane];
#pragma unroll
                        for (int xi = 0; xi < XPW; ++xi) {
                            acc_h[xi][ct] = __builtin_amdgcn_mfma_f32_16x16x32_f16(ah, bf[xi], acc_h[xi][ct], 0, 0, 0);
                            acc_l[xi][ct] = __builtin_amdgcn_mfma_f32_16x16x32_f16(al, bf[xi], acc_l[xi][ct], 0, 0, 0);
                        }
                    }
                }
            }
        }
        // C/D layout: col = lane&15 (= t), row = (lane>>4)*4 + r (= cout)
#pragma unroll
        for (int xi = 0; xi < XPW; ++xi) {
            int x = wv * XPW + xi;
#pragma unroll
            for (int ct = 0; ct < CT; ++ct) {
#pragma unroll
                for (int r = 0; r < 4; ++r) {
                    int co = ct * 16 + hi * 4 + r;
                    int pz = ((n * COUT + co) * H + (yb + yy)) * W + x;
                    z[((size_t)tc * NP + pz) * 16 + tl]
                        = acc_h[xi][ct][r] + acc_l[xi][ct][r] * 2.44140625e-4f;
                }
            }
        }
    }
}

// MFMA FC: out[n][co][t] = sum_f w[co][f] * s16[n][t][f]. Output z6 [n][co][300] f32.
template <int FIN, int OUT>
__global__ void __launch_bounds__(256) k_fc_mfma(const _Float16* __restrict__ s16,
                                                 const _Float16* __restrict__ wm,
                                                 float* __restrict__ z) {
    constexpr int NT = 19;
    constexpr int CT = OUT / 16;
    constexpr int KCH = 512;
    constexpr int NK = FIN / KCH;
    __shared__ _Float16 lds[KCH * 16];   // 16 KB

    int bid = blockIdx.x;           // grid = (CT/4) * NBATCH * NT
    int tc = bid % NT;
    int n  = (bid / NT) % NBATCH;
    int cg = bid / (NT * NBATCH);
    int tid = threadIdx.x;
    int lane = tid & 63, wv = tid >> 6;
    int tl = lane & 15, hi = lane >> 4;
    int ct = cg * 4 + wv;

    f32x4 acc_h = (f32x4){0.f, 0.f, 0.f, 0.f};
    f32x4 acc_l = (f32x4){0.f, 0.f, 0.f, 0.f};
    const h8t* wmv = (const h8t*)wm;

    for (int kb = 0; kb < NK; ++kb) {
        __syncthreads();
#pragma unroll
        for (int j = 0; j < 4; ++j) {
            int chunk = tid + j * 256;
            int c = chunk & 63;
            int t = chunk >> 6;
            int tg = tc * 16 + t;
            h8t v;
#pragma unroll
            for (int e = 0; e < 8; ++e) v[e] = (_Float16)0.0f;
            if (tg < TT) v = *(const h8t*)(s16 + ((size_t)(n * TT + tg) * FIN + kb * KCH + c * 8));
            *(h8t*)(lds + ((t * 64 + (c ^ (t & 7))) << 3)) = v;
        }
        __syncthreads();
#pragma unroll
        for (int kc = 0; kc < KCH / 32; ++kc) {
            int c = kc * 4 + hi;
            h8t bf = *(const h8t*)(lds + ((tl * 64 + (c ^ (tl & 7))) << 3));
            size_t wbase = ((size_t)((kb * (KCH / 32) + kc) * CT + ct)) * 2;
            h8t ah = wmv[(wbase + 0) * 64 + lane];
            h8t al = wmv[(wbase + 1) * 64 + lane];
            acc_h = __builtin_amdgcn_mfma_f32_16x16x32_f16(ah, bf, acc_h, 0, 0, 0);
            acc_l = __builtin_amdgcn_mfma_f32_16x16x32_f16(al, bf, acc_l, 0, 0, 0);
        }
    }
    int tg = tc * 16 + tl;
    if (tg < TT) {
#pragma unroll
        for (int r = 0; r < 4; ++r) {
            int co = ct * 16 + hi * 4 + r;
            z[(size_t)(n * OUT + co) * TT + tg] = acc_h[r] + acc_l[r] * 2.44140625e-4f;
        }
    }
}

// FC with packed fp32 FMA over the t dimension (tiny L7 11x256).
template <int OUT, int FIN, int OPER, int FSPLIT>
__global__ void k_fc_a(const float* __restrict__ s, const float* __restrict__ wgt,
                       float* __restrict__ z) {
    constexpr int OG = OUT / OPER, FCH = FIN / FSPLIT;
    int idx = blockIdx.x * 256 + threadIdx.x;
    if (idx >= NBATCH * OG * TC * FSPLIT) return;
    int tc = idx % TC;
    int og = (idx / TC) % OG;
    int n  = (idx / (TC * OG)) % NBATCH;
    int sp = idx / (TC * OG * NBATCH);
    const float* sb = s + (size_t)n * FIN * TT + (size_t)sp * FCH * TT + tc * 4;
    const float* wb = wgt + (size_t)sp * FCH;
    pf2 acc[OPER][2];
#pragma unroll
    for (int k = 0; k < OPER; ++k) { acc[k][0] = (pf2){0.f, 0.f}; acc[k][1] = (pf2){0.f, 0.f}; }
#pragma unroll 2
    for (int f = 0; f < FCH; f += 4) {
        float4 s0 = *(const float4*)(sb + (size_t)(f + 0) * TT);
        float4 s1 = *(const float4*)(sb + (size_t)(f + 1) * TT);
        float4 s2 = *(const float4*)(sb + (size_t)(f + 2) * TT);
        float4 s3 = *(const float4*)(sb + (size_t)(f + 3) * TT);
        pf2 s0a = {s0.x, s0.y}, s0b = {s0.z, s0.w};
        pf2 s1a = {s1.x, s1.y}, s1b = {s1.z, s1.w};
        pf2 s2a = {s2.x, s2.y}, s2b = {s2.z, s2.w};
        pf2 s3a = {s3.x, s3.y}, s3b = {s3.z, s3.w};
#pragma unroll
        for (int k = 0; k < OPER; ++k) {
            float4 wv = *(const float4*)(wb + (size_t)(og * OPER + k) * FIN + f);
            pf2 wx = {wv.x, wv.x}, wy = {wv.y, wv.y}, wz = {wv.z, wv.z}, ww = {wv.w, wv.w};
            pf2 a0 = acc[k][0], a1 = acc[k][1];
            a0 = __builtin_elementwise_fma(wx, s0a, a0);
            a0 = __builtin_elementwise_fma(wy, s1a, a0);
            a0 = __builtin_elementwise_fma(wz, s2a, a0);
            a0 = __builtin_elementwise_fma(ww, s3a, a0);
            a1 = __builtin_elementwise_fma(wx, s0b, a1);
            a1 = __builtin_elementwise_fma(wy, s1b, a1);
            a1 = __builtin_elementwise_fma(wz, s2b, a1);
            a1 = __builtin_elementwise_fma(ww, s3b, a1);
            acc[k][0] = a0; acc[k][1] = a1;
        }
    }
#pragma unroll
    for (int k = 0; k < OPER; ++k) {
        float4 o;
        o.x = acc[k][0].x; o.y = acc[k][0].y; o.z = acc[k][1].x; o.w = acc[k][1].y;
        *(float4*)(z + ((size_t)sp * NBATCH * OUT + (size_t)n * OUT + og * OPER + k) * TT + tc * 4) = o;
    }
}

extern "C" void kernel_launch(void* const* d_in, const int* in_sizes, int n_in,
                              void* d_out, int out_size, void* d_ws, size_t ws_size,
                              hipStream_t stream) {
    const float* s_in = (const float*)d_in[0]; // (4,2,128,128,300)
    const float* w1   = (const float*)d_in[1]; // (32,2,5,5)
    const float* w2   = (const float*)d_in[2]; // (64,32,3,3)
    const float* w3   = (const float*)d_in[3]; // (64,64,3,3)
    const float* w4a  = (const float*)d_in[4]; // (256,4096)
    const float* w4b  = (const float*)d_in[5]; // (11,256)
    float* out = (float*)d_out;                // (4,11,300)

    // Workspace map (floats): Z 39,321,600 | Sb 9,830,400 | WP 56,896.
    // Z: z3 [tc][65536][16] = 19.92M floats at [0..); z5 [tc][16384][16] = 4.98M;
    //    S16 @ Z+25M (2.46M f); wm4 @ Z+28M (1.05M f); wl1m @ Z+30M.
    // Sb: s0 f32 [0..2.46M); s2h f16 @ Sb+2.5M; s4h f16 @ Sb+5M (sequential liveness);
    //     s6 f32 reuses Sb[0..).
    float* Z  = (float*)d_ws;
    float* Sb = Z + 39321600;
    float* WP = Sb + 9830400;
    _Float16* wm2 = (_Float16*)(WP + 1600);
    _Float16* wm3 = (_Float16*)(WP + 1600 + 18432);
    _Float16* S16 = (_Float16*)(Z + 25000000);
    _Float16* wm4 = (_Float16*)(Z + 28000000);
    _Float16* wl1m = (_Float16*)(Z + 30000000);          // 6144 halves
    float* s0 = Sb;                                      // f32 (4,2,32,32,300)
    _Float16* s2h = (_Float16*)(Sb + 2500000);           // f16 [n][4][16][16][300][8]
    _Float16* s4h = (_Float16*)(Sb + 5000000);           // f16 [n][8][8][8][300][8]

    auto g = [](int n) { return (n + 255) / 256; };
    auto g64 = [](int n) { return (n + 63) / 64; };

    // weight packs (independent of activations; Z high region never aliases z3/z5)
    k_pack_wl1<<<3, 256, 0, stream>>>(w1, wl1m);
    k_pack_wmfma<<<g(4608), 256, 0, stream>>>(w2, wm2, 32, 64, 4608);
    k_pack_wmfma<<<g(9216), 256, 0, stream>>>(w3, wm3, 64, 64, 9216);
    k_pack_wfc<<<g(262144), 256, 0, stream>>>(w4a, wm4, 4096, 256, 262144);

    // L0: 4x4 pool + psp -> s0 (4,2,32,32,300) f32 @ Sb
    k_pool4<<<g(614400), 256, 0, stream>>>(s_in, Z);
    k_scan_redp<1><<<g64(8192), 64, 0, stream>>>(Z, s0, 8192, 0);

    // L1 fused, single-wave blocks: conv 5x5 MFMA + psp + pool + psp -> s2h. grid 2048.
    k_l1_w64<<<2048, 64, 0, stream>>>(s0, wl1m, s2h);

    // L3 conv 3x3 (32->64, 16x16) MFMA, YPB=2: z3 [tc][p][16] @ Z. grid 19*8*4 = 608.
    k_conv_mfma<32, 64, 16, 16, 2><<<608, 256, 0, stream>>>(s2h, wm2, Z);
    // L3 psp + 2x2 pool + L4 psp -> s4h f16 conv-native. 256 blocks.
    k_spsq16<64, 8, 8><<<256, 256, 0, stream>>>(Z, s4h);

    // L5 conv 3x3 (64->64, 8x8) MFMA, YPB=1: z5 [tc][p][16] @ Z. grid 19*8*4 = 608.
    k_conv_mfma<64, 64, 8, 8, 1><<<608, 256, 0, stream>>>(s4h, wm3, Z);
    // psp scan -> f16 spikes [n][t][f] @ S16 (16384 neurons).
    k_scan16_f16<<<256, 64, 0, stream>>>(Z, S16);

    // L6: fc 4096->256 MFMA: z6 (4,256,300) @ Z. grid = 4 cog * 4 n * 19 tc = 304.
    k_fc_mfma<4096, 256><<<304, 256, 0, stream>>>(S16, wm4, Z);
    k_scan_redp<1><<<g64(1024), 64, 0, stream>>>(Z, Sb, 1024, 0);

    // L7: fc 256->11 + psp -> out
    k_fc_a<11, 256, 1, 1><<<g(3300), 256, 0, stream>>>(Sb, w4b, Z);
    k_scan_redp<1><<<1, 64, 0, stream>>>(Z, out, 44, 0);
}

// Round 7
// 545.770 us; speedup vs baseline: 1.1659x; 1.1659x over previous
//
#include <hip/hip_runtime.h>
#include <cstdint>

#define TT 300   // timesteps
#define TC 75    // TT/4
#define NBATCH 4

typedef float pf2 __attribute__((ext_vector_type(2)));   // packs to v_pk_fma_f32
typedef _Float16 h8t __attribute__((ext_vector_type(8)));  // 4 VGPRs = MFMA f16 A/B frag
typedef float f32x4 __attribute__((ext_vector_type(4)));   // MFMA C/D frag

// PSP + refractory IIR step, exact op order of the reference scan.
__device__ __forceinline__ void psp_step(float z, float& gp, float& hp, float& gr, float& hr, float& s_out) {
    hp = 0.90483741803595957f * (hp + gp);      // a_sr = exp(-1/10)
    gp = 0.90483741803595957f * gp + z;
    hr = 0.36787944117144233f * (hr + gr);      // a_rf = exp(-1)
    gr = 0.36787944117144233f * gr;
    float u = 0.27182818284590452f * hp + (-54.365636569180904f) * hr; // c_sr*hp + c_rf*hr
    float s = (u >= 10.0f) ? 1.0f : 0.0f;
    gr += s;
    s_out = s;
}

// Per-neuron scan over T, 12-step chunks, [p][300] layout (used for L0 and L6).
template <int R>
__global__ void k_scan_redp(const float* __restrict__ z, float* __restrict__ s,
                            int n_neur, int pstride) {
    int i = blockIdx.x * 64 + threadIdx.x;
    if (i >= n_neur) return;
    const float* zp = z + (size_t)i * TT;
    float* sp = s + (size_t)i * TT;
    float gp = 0.f, hp = 0.f, gr = 0.f, hr = 0.f;
#pragma unroll 1
    for (int c = 0; c < 25; ++c) {
        const float* p = zp + c * 12;
        float4 a0 = *(const float4*)(p);
        float4 a1 = *(const float4*)(p + 4);
        float4 a2 = *(const float4*)(p + 8);
#pragma unroll
        for (int r = 1; r < R; ++r) {
            const float* pr = p + (size_t)r * pstride;
            float4 b0 = *(const float4*)(pr);
            float4 b1 = *(const float4*)(pr + 4);
            float4 b2 = *(const float4*)(pr + 8);
            a0.x += b0.x; a0.y += b0.y; a0.z += b0.z; a0.w += b0.w;
            a1.x += b1.x; a1.y += b1.y; a1.z += b1.z; a1.w += b1.w;
            a2.x += b2.x; a2.y += b2.y; a2.z += b2.z; a2.w += b2.w;
        }
        float4 o0, o1, o2;
        psp_step(a0.x, gp, hp, gr, hr, o0.x);
        psp_step(a0.y, gp, hp, gr, hr, o0.y);
        psp_step(a0.z, gp, hp, gr, hr, o0.z);
        psp_step(a0.w, gp, hp, gr, hr, o0.w);
        psp_step(a1.x, gp, hp, gr, hr, o1.x);
        psp_step(a1.y, gp, hp, gr, hr, o1.y);
        psp_step(a1.z, gp, hp, gr, hr, o1.z);
        psp_step(a1.w, gp, hp, gr, hr, o1.w);
        psp_step(a2.x, gp, hp, gr, hr, o2.x);
        psp_step(a2.y, gp, hp, gr, hr, o2.y);
        psp_step(a2.z, gp, hp, gr, hr, o2.z);
        psp_step(a2.w, gp, hp, gr, hr, o2.w);
        float* q = sp + c * 12;
        *(float4*)(q) = o0;
        *(float4*)(q + 4) = o1;
        *(float4*)(q + 8) = o2;
    }
}

// Scan for L5 output: reads z5 in [tc][p][16] layout (p = n*4096 + f), writes f16
// spikes S16 [n][t][4096]. Wave reads are 64 lanes x 64B contiguous = 4KB segments.
__global__ void k_scan16_f16(const float* __restrict__ z, _Float16* __restrict__ s16) {
    int i = blockIdx.x * 64 + threadIdx.x;     // 16384 neurons, grid 256 x 64
    int n = i >> 12, f = i & 4095;
    const float* zp = z + (size_t)i * 16;
    _Float16* sp = s16 + ((size_t)n * TT) * 4096 + f;
    float gp = 0.f, hp = 0.f, gr = 0.f, hr = 0.f;
#define SC16_CHUNK(TCI, NTT) do {                                              \
    const float* pp = zp + (size_t)(TCI) * (16384 * 16);                       \
    float4 a0 = *(const float4*)(pp);                                          \
    float4 a1 = *(const float4*)(pp + 4);                                      \
    float4 a2 = *(const float4*)(pp + 8);                                      \
    float4 a3 = *(const float4*)(pp + 12);                                     \
    float zv[16] = {a0.x,a0.y,a0.z,a0.w,a1.x,a1.y,a1.z,a1.w,                   \
                    a2.x,a2.y,a2.z,a2.w,a3.x,a3.y,a3.z,a3.w};                  \
    _Pragma("unroll")                                                          \
    for (int tt = 0; tt < (NTT); ++tt) {                                       \
        float o;                                                               \
        psp_step(zv[tt], gp, hp, gr, hr, o);                                   \
        sp[(size_t)((TCI) * 16 + tt) * 4096] = (_Float16)o;                    \
    }                                                                          \
} while (0)
#pragma unroll 1
    for (int tcc = 0; tcc < 18; ++tcc) SC16_CHUNK(tcc, 16);
    SC16_CHUNK(18, 12);
#undef SC16_CHUNK
}

// Fused scan-pool-scan for L3 output: reads z3 [tc][p][16] (p = ((n*C+c)*H+y)*W+x),
// emits f16 spikes conv-native [n][c/8][y2][x2][t][8].
template <int C, int H2, int W2>
__global__ void __launch_bounds__(256) k_spsq16(const float* __restrict__ z,
                                                _Float16* __restrict__ s16) {
    constexpr int H = 2 * H2, W = 2 * W2;
    constexpr int NP = NBATCH * C * H * W;
    constexpr int C8 = C / 8;
    __shared__ _Float16 tile[16 * C];

    int i = blockIdx.x * 256 + threadIdx.x;    // grid exact: N*C*H2*W2*4 threads
    int q = i & 3;
    int p = i >> 2;
    int c  = p % C;
    int x2 = (p / C) % W2;
    int y2 = (p / (C * W2)) % H2;
    int n  = p / (C * W2 * H2);
    int dy = q >> 1, dx = q & 1;
    int pz = ((n * C + c) * H + 2 * y2 + dy) * W + 2 * x2 + dx;
    const float* zp = z + (size_t)pz * 16;

    int tid = threadIdx.x;
    int wt  = tid & 15;
    int wc8 = tid >> 4;
    int p0 = blockIdx.x * 64;                  // block's site (C-aligned p)
    int wx2 = (p0 / C) % W2;
    int wy2 = (p0 / (C * W2)) % H2;
    int wn  = p0 / (C * W2 * H2);
    _Float16* wbase = s16 + ((((size_t)(wn * C8 + wc8) * H2 + wy2) * W2 + wx2) * TT) * 8;

    float gp = 0.f, hp = 0.f, gr = 0.f, hr = 0.f;   // conv neuron IIR
    float Gp = 0.f, Hp = 0.f, Gr = 0.f, Hr = 0.f;   // pooled neuron IIR
#define SPSQ_CHUNK(TCI, NTT) do {                                              \
    const float* pp = zp + (size_t)(TCI) * (NP * 16);                          \
    float4 a0 = *(const float4*)(pp);                                          \
    float4 a1 = *(const float4*)(pp + 4);                                      \
    float4 a2 = *(const float4*)(pp + 8);                                      \
    float4 a3 = *(const float4*)(pp + 12);                                     \
    float zv[16] = {a0.x,a0.y,a0.z,a0.w,a1.x,a1.y,a1.z,a1.w,                   \
                    a2.x,a2.y,a2.z,a2.w,a3.x,a3.y,a3.z,a3.w};                  \
    float ov[16];                                                              \
    _Pragma("unroll")                                                          \
    for (int tt = 0; tt < (NTT); ++tt) {                                       \
        float sq;                                                              \
        psp_step(zv[tt], gp, hp, gr, hr, sq);                                  \
        float t1 = sq + __shfl_xor(sq, 1, 64);                                 \
        float pool = t1 + __shfl_xor(t1, 2, 64);                               \
        psp_step(11.0f * pool, Gp, Hp, Gr, Hr, ov[tt]);                        \
    }                                                                          \
    __syncthreads();                                                           \
    if (q == 0) {                                                              \
        _Pragma("unroll")                                                      \
        for (int tt = 0; tt < (NTT); ++tt)                                     \
            tile[tt * C + c] = (_Float16)ov[tt];                               \
    }                                                                          \
    __syncthreads();                                                           \
    if (tid < 16 * C8 && wt < (NTT)) {                                         \
        h8t v = *(const h8t*)(tile + wt * C + wc8 * 8);                        \
        *(h8t*)(wbase + (size_t)((TCI) * 16 + wt) * 8) = v;                    \
    }                                                                          \
} while (0)
#pragma unroll 1
    for (int tcc = 0; tcc < 18; ++tcc) SPSQ_CHUNK(tcc, 16);
    SPSQ_CHUNK(18, 12);
#undef SPSQ_CHUNK
}

// Pack 3x3 OIHW conv weights into MFMA A-fragments with f16 hi/lo split.
// Layout: [tap 9][kc CIN/32][ct COUT/16][ver 2][lane 64][j 8] halves.
__global__ void k_pack_wmfma(const float* __restrict__ w, _Float16* __restrict__ wm,
                             int CIN, int COUT, int total) {
    int i = blockIdx.x * 256 + threadIdx.x;
    if (i >= total) return;
    int lane = i & 63;
    int r = i >> 6;
    int ver = r & 1; r >>= 1;
    int KC = CIN >> 5, CT = COUT >> 4;
    int ct = r % CT; r /= CT;
    int kc = r % KC;
    int tap = r / KC;
    int ky = tap / 3, kx = tap % 3;
    int co  = ct * 16 + (lane & 15);
    int ci0 = kc * 32 + (lane >> 4) * 8;
    _Float16 out[8];
#pragma unroll
    for (int j = 0; j < 8; ++j) {
        float wf = w[((co * CIN + ci0 + j) * 3 + ky) * 3 + kx];
        _Float16 hi = (_Float16)wf;
        out[j] = ver ? (_Float16)((wf - (float)hi) * 4096.0f) : hi;
    }
    *(h8t*)(wm + (size_t)i * 8) = *(h8t*)out;
}

// Pack FC weights (COUT, FIN) row-major into MFMA A-fragments, hi/lo split.
__global__ void k_pack_wfc(const float* __restrict__ w, _Float16* __restrict__ wm,
                           int FIN, int COUT, int total) {
    int i = blockIdx.x * 256 + threadIdx.x;
    if (i >= total) return;
    int lane = i & 63;
    int r = i >> 6;
    int ver = r & 1; r >>= 1;
    int CT = COUT >> 4;
    int ct = r % CT;
    int kg = r / CT;
    int co = ct * 16 + (lane & 15);
    int f0 = kg * 32 + (lane >> 4) * 8;
    _Float16 out[8];
#pragma unroll
    for (int j = 0; j < 8; ++j) {
        float wf = w[(size_t)co * FIN + f0 + j];
        _Float16 hi = (_Float16)wf;
        out[j] = ver ? (_Float16)((wf - (float)hi) * 4096.0f) : hi;
    }
    *(h8t*)(wm + (size_t)i * 8) = *(h8t*)out;
}

// Pack L1 5x5 (32,2,5,5) weights into padded-K MFMA A-frags, hi/lo split.
// K = 96: k -> ky = k>>4, slot = k&15, kx = slot>>1, ci = slot&1; pad slots zero.
__global__ void k_pack_wl1(const float* __restrict__ w, _Float16* __restrict__ wm) {
    int i = blockIdx.x * 256 + threadIdx.x;
    if (i >= 768) return;
    int lane = i & 63;
    int r = i >> 6;
    int ver = r & 1;
    int ch = (r >> 1) & 1;
    int kc = r >> 2;
    int co = ch * 16 + (lane & 15);
    int k0 = kc * 32 + (lane >> 4) * 8;
    _Float16 out[8];
#pragma unroll
    for (int j = 0; j < 8; ++j) {
        int k = k0 + j;
        int ky = k >> 4, slot = k & 15, kx = slot >> 1, ci = slot & 1;
        float wf = (ky < 5 && kx < 5) ? w[((co * 2 + ci) * 5 + ky) * 5 + kx] : 0.f;
        _Float16 hif = (_Float16)wf;
        out[j] = ver ? (_Float16)((wf - (float)hif) * 4096.0f) : hif;
    }
    *(h8t*)(wm + (size_t)i * 8) = *(h8t*)out;
}

// 4x4 sum-pool * 11.0 over (N,2,128,128,T) -> z (N,2,32,32,T). Thread = (p, tc), tc fastest.
__global__ void k_pool4(const float* __restrict__ x, float* __restrict__ z) {
    int idx = blockIdx.x * 256 + threadIdx.x;
    if (idx >= NBATCH * 2 * 32 * 32 * TC) return;
    int tc = idx % TC;
    int p  = idx / TC;
    int w  = p % 32;
    int h  = (p / 32) % 32;
    int nc = p / (32 * 32);
    const float* base = x + (((size_t)nc * 128 + h * 4) * 128 + w * 4) * TT + tc * 4;
    float ax = 0.f, ay = 0.f, az = 0.f, aw = 0.f;
#pragma unroll
    for (int i = 0; i < 4; ++i)
#pragma unroll
        for (int j = 0; j < 4; ++j) {
            float4 v = *(const float4*)(base + ((size_t)i * 128 + j) * TT);
            ax += v.x; ay += v.y; az += v.z; aw += v.w;
        }
    float4 o; o.x = 11.0f * ax; o.y = 11.0f * ay; o.z = 11.0f * az; o.w = 11.0f * aw;
    *(float4*)(z + (size_t)p * TT + tc * 4) = o;
}

// Fused L1 (v2): 5x5 conv (2->32) MFMA + psp + 2x2 pool + psp -> s2h f16 conv-native.
// Block = (n, ch co-half, xh x-octet, y2 pool-row) owns ALL 300 t (IIR in VGPRs).
// v2 vs round-4 (131.7 us, 6.46M bank-conflict cycles):
//  (a) stage stride 40 -> 42 halves (21 words, odd): B-frag dword reads spread over
//      all 32 banks (was (20*tl)%32 -> 8 banks, 8-way conflict).
//  (b) T14 async staging: per-thread stage geometry is tile-invariant (hoisted);
//      next tile's s0 values loaded as float4-over-t (t contiguous in s0) into regs
//      BEFORE the long scan phase -> HBM latency hides under scan VALU; LDS write
//      from regs at top of next tile. 3.5x fewer load instructions too.
//  (c) 3 barriers/tile (loop-top barrier was redundant); weights hoisted to regs.
// Numerics: identical values and op order to round-4 -> absmax unchanged (0.0).
__global__ void __launch_bounds__(256) k_l1_fused(const float* __restrict__ s0,
                                                  const _Float16* __restrict__ wl1,
                                                  _Float16* __restrict__ s2h) {
    constexpr int NT = 19;
    __shared__ _Float16 stage[7 * 16 * 42];   // [row7][t16][42: 16lx x 2ci + 10 pad]
    __shared__ float    trans[256 * 17];      // [neuron 256][16 t + 1 pad]
    __shared__ _Float16 tile[4 * 16 * 16];    // [x2l][t][co]

    int bid = blockIdx.x;                     // grid 512 = n4 * ch2 * xh4 * y2_16
    int y2 = bid & 15;
    int xh = (bid >> 4) & 3;
    int ch = (bid >> 6) & 1;
    int n  = bid >> 7;
    int tid = threadIdx.x;
    int lane = tid & 63;
    int wv = tid >> 6;          // 4 waves: (yy, xq)
    int tl = lane & 15;
    int hi = lane >> 4;
    int yy = wv >> 1;
    int xq = wv & 1;

    int q    = tid & 3;         // scan role: dy=q>>1, dx=q&1 (lane bits 0-1 -> shfl pool)
    int co_s = (tid >> 2) & 15;
    int x2l_s = tid >> 6;
    int wt  = tid & 15;         // writer role (tid<128)
    int wc8 = (tid >> 4) & 1;
    int wx  = tid >> 5;

    // per-thread stage geometry: 4 items, item i = (r, ci, lx, tq); t = tq*4+e.
    // 7r x 2ci x 16lx x 4tq = 896 items over 256 threads.
    bool   it_v[4];
    size_t it_off[4];
    int    it_adr[4];
    int    it_tq[4];
#pragma unroll
    for (int ii = 0; ii < 4; ++ii) {
        int i = tid + ii * 256;
        int tq = i & 3;
        int lx = (i >> 2) & 15;
        int ci = (i >> 6) & 1;
        int r  = i >> 7;
        int gx = xh * 8 + lx - 2;
        int gy = y2 * 2 + r - 2;
        bool sp = (i < 896) && gx >= 0 && gx < 32 && gy >= 0 && gy < 32;
        it_v[ii]   = sp;
        it_off[ii] = sp ? ((((size_t)(n * 2 + ci) * 32 + gy) * 32 + gx) * TT + tq * 4) : 0;
        it_adr[ii] = (r * 16 + tq * 4) * 42 + lx * 2 + ci;
        it_tq[ii]  = tq;
    }

    // weights hoisted: [kc3][ver2] A-frags (lane-indexed)
    const h8t* wv4 = (const h8t*)wl1;
    h8t wfr[3][2];
#pragma unroll
    for (int kc = 0; kc < 3; ++kc) {
        wfr[kc][0] = wv4[((kc * 2 + ch) * 2 + 0) * 64 + lane];
        wfr[kc][1] = wv4[((kc * 2 + ch) * 2 + 1) * 64 + lane];
    }

    float gp = 0.f, hp = 0.f, gr = 0.f, hr = 0.f;
    float Gp = 0.f, Hp = 0.f, Gr = 0.f, Hr = 0.f;

    // prologue prefetch: tile 0 (all tq in range: tg <= 15 < 300)
    float4 pf[4];
#pragma unroll
    for (int ii = 0; ii < 4; ++ii) {
        pf[ii] = make_float4(0.f, 0.f, 0.f, 0.f);
        if (it_v[ii]) pf[ii] = *(const float4*)(s0 + it_off[ii]);
    }

#pragma unroll 1
    for (int tc = 0; tc < NT; ++tc) {
        // stage write from prefetched regs (f32 -> f16)
#pragma unroll
        for (int ii = 0; ii < 4; ++ii) {
            if (tid + ii * 256 < 896) {
                stage[it_adr[ii] + 0 * 42] = (_Float16)pf[ii].x;
                stage[it_adr[ii] + 1 * 42] = (_Float16)pf[ii].y;
                stage[it_adr[ii] + 2 * 42] = (_Float16)pf[ii].z;
                stage[it_adr[ii] + 3 * 42] = (_Float16)pf[ii].w;
            }
        }
        // issue next tile's loads now — in flight across MFMA + scan phases
        if (tc + 1 < NT) {
#pragma unroll
            for (int ii = 0; ii < 4; ++ii) {
                float4 v = make_float4(0.f, 0.f, 0.f, 0.f);
                if (it_v[ii] && (tc + 1) * 16 + it_tq[ii] * 4 + 3 < TT)
                    v = *(const float4*)(s0 + it_off[ii] + (tc + 1) * 16);
                pf[ii] = v;
            }
        }
        __syncthreads();   // [B] stage ready
        // MFMA: wave (yy,xq) -> 16 co x 4 xo x 16 t. A k = kc*32+hi*8+j ->
        // ky = 2kc+(hi>>1), slot = (hi&1)*8+j; B = stage[(yy+2kc+(hi>>1))*16+tl][xo*2+slot].
        f32x4 ah4[4], al4[4];
#pragma unroll
        for (int xi = 0; xi < 4; ++xi) { ah4[xi] = (f32x4){0.f,0.f,0.f,0.f}; al4[xi] = (f32x4){0.f,0.f,0.f,0.f}; }
#pragma unroll
        for (int kc = 0; kc < 3; ++kc) {
            int row = yy + 2 * kc + (hi >> 1);
#pragma unroll
            for (int xi = 0; xi < 4; ++xi) {
                int xo = xq * 4 + xi;
                const uint32_t* lp = (const uint32_t*)(stage + (row * 16 + tl) * 42 + xo * 2 + (hi & 1) * 8);
                union { uint32_t u[4]; h8t h; } bu;
                bu.u[0] = lp[0]; bu.u[1] = lp[1]; bu.u[2] = lp[2]; bu.u[3] = lp[3];
                ah4[xi] = __builtin_amdgcn_mfma_f32_16x16x32_f16(wfr[kc][0], bu.h, ah4[xi], 0, 0, 0);
                al4[xi] = __builtin_amdgcn_mfma_f32_16x16x32_f16(wfr[kc][1], bu.h, al4[xi], 0, 0, 0);
            }
        }
        // transpose -> trans[neuron][t]; neuron = (x2l*16+co)*4 + dy*2 + dx.
#pragma unroll
        for (int xi = 0; xi < 4; ++xi) {
            int xo = xq * 4 + xi;
#pragma unroll
            for (int r = 0; r < 4; ++r) {
                float u = ah4[xi][0 * 0 + r] + al4[xi][r] * 2.44140625e-4f;
                int rowt = ((xo >> 1) * 16 + hi * 4 + r) * 4 + yy * 2 + (xo & 1);
                trans[rowt * 17 + tl] = u;
            }
        }
        __syncthreads();   // [C] trans ready
        // scan: each thread = 1 conv neuron; quad (lane bits 0-1) pools via shfl.
#pragma unroll
        for (int t = 0; t < 16; ++t) {
            float u = trans[tid * 17 + t];
            float sq;
            psp_step(u, gp, hp, gr, hr, sq);
            float t1 = sq + __shfl_xor(sq, 1, 64);
            float pool = t1 + __shfl_xor(t1, 2, 64);
            float ov;
            psp_step(11.0f * pool, Gp, Hp, Gr, Hr, ov);
            if (q == 0) tile[(x2l_s * 16 + t) * 16 + co_s] = (_Float16)ov;
        }
        __syncthreads();   // [D] tile ready
        // write pooled spikes: [n][cg8 4][y2 16][x2 16][t 300][8]
        if (tid < 128) {
            int tg = tc * 16 + wt;
            if (tg < TT) {
                h8t v = *(const h8t*)(tile + (wx * 16 + wt) * 16 + wc8 * 8);
                int cg8 = ch * 2 + wc8;
                int x2g = xh * 4 + wx;
                *(h8t*)(s2h + ((((size_t)(n * 4 + cg8) * 16 + y2) * 16 + x2g) * (size_t)TT + tg) * 8) = v;
            }
        }
    }
}

// MFMA 3x3 conv (pad 1). Input: f16 spikes [n][ci/8][y][x][t][8]. Output z in
// [tc][p][16] layout. Round-3 proven occupancy config: launch_bounds(256,2).
template <int CIN, int COUT, int H, int W, int YPB>
__global__ void __launch_bounds__(256, 2) k_conv_mfma(const _Float16* __restrict__ s16,
                                                      const _Float16* __restrict__ wm,
                                                      float* __restrict__ z) {
    constexpr int NT = 19;          // ceil(300/16)
    constexpr int KC = CIN / 32;
    constexpr int CH = CIN / 8;
    constexpr int XL = W + 2;
    constexpr int CT = COUT / 16;
    constexpr int XPW = W / 4;
    constexpr int ROWS = YPB + 2;
    constexpr int NP = NBATCH * COUT * H * W;
    __shared__ _Float16 lds[ROWS * XL * 16 * CIN];

    int bid = blockIdx.x;
    int tc = bid % NT;
    int yb = ((bid / NT) % (H / YPB)) * YPB;
    int n  = bid / (NT * (H / YPB));
    int tid = threadIdx.x;

    constexpr int TOT = ROWS * XL * CH * 16;
    for (int i = tid; i < TOT; i += 256) {
        int t   = i & 15;
        int c   = (i >> 4) % CH;
        int xc  = ((i >> 4) / CH) % XL;
        int row = ((i >> 4) / CH) / XL;
        int tg = tc * 16 + t;
        int xi = xc - 1;
        int yi = yb + row - 1;
        h8t v;
#pragma unroll
        for (int e = 0; e < 8; ++e) v[e] = (_Float16)0.0f;
        if (xi >= 0 && xi < W && yi >= 0 && yi < H && tg < TT)
            v = *(const h8t*)(s16 + ((((size_t)(n * CH + c) * H + yi) * W + xi) * TT + tg) * 8);
        int swz = (CIN == 32) ? ((t >> 1) & 3) : (t & 7);
        int off = ((row * XL + xc) * 16 + t) * CIN + ((c ^ swz) << 3);
        *(h8t*)(lds + off) = v;
    }
    __syncthreads();

    int lane = tid & 63;
    int wv   = tid >> 6;
    int tl   = lane & 15;
    int hi   = lane >> 4;
    const h8t* wmv = (const h8t*)wm;
    int swz = (CIN == 32) ? ((tl >> 1) & 3) : (tl & 7);

#pragma unroll
    for (int yy = 0; yy < YPB; ++yy) {
        f32x4 acc_h[XPW][CT], acc_l[XPW][CT];
#pragma unroll
        for (int a = 0; a < XPW; ++a)
#pragma unroll
            for (int b = 0; b < CT; ++b) {
                acc_h[a][b] = (f32x4){0.f, 0.f, 0.f, 0.f};
                acc_l[a][b] = (f32x4){0.f, 0.f, 0.f, 0.f};
            }
#pragma unroll
        for (int ky = 0; ky < 3; ++ky) {
#pragma unroll
            for (int kx = 0; kx < 3; ++kx) {
                int tap = ky * 3 + kx;
#pragma unroll
                for (int kc = 0; kc < KC; ++kc) {
                    h8t bf[XPW];
#pragma unroll
                    for (int xi = 0; xi < XPW; ++xi) {
                        int x = wv * XPW + xi;
                        int c = kc * 4 + hi;
                        int off = (((yy + ky) * XL + (x + kx)) * 16 + tl) * CIN + ((c ^ swz) << 3);
                        bf[xi] = *(const h8t*)(lds + off);
                    }
#pragma unroll
                    for (int ct = 0; ct < CT; ++ct) {
                        size_t wbase = ((size_t)(tap * KC + kc) * CT + ct) * 2;
                        h8t ah = wmv[(wbase + 0) * 64 + lane];
                        h8t al = wmv[(wbase + 1) * 64 + lane];
#pragma unroll
                        for (int xi = 0; xi < XPW; ++xi) {
                            acc_h[xi][ct] = __builtin_amdgcn_mfma_f32_16x16x32_f16(ah, bf[xi], acc_h[xi][ct], 0, 0, 0);
                            acc_l[xi][ct] = __builtin_amdgcn_mfma_f32_16x16x32_f16(al, bf[xi], acc_l[xi][ct], 0, 0, 0);
                        }
                    }
                }
            }
        }
        // C/D layout: col = lane&15 (= t), row = (lane>>4)*4 + r (= cout)
#pragma unroll
        for (int xi = 0; xi < XPW; ++xi) {
            int x = wv * XPW + xi;
#pragma unroll
            for (int ct = 0; ct < CT; ++ct) {
#pragma unroll
                for (int r = 0; r < 4; ++r) {
                    int co = ct * 16 + hi * 4 + r;
                    int pz = ((n * COUT + co) * H + (yb + yy)) * W + x;
                    z[((size_t)tc * NP + pz) * 16 + tl]
                        = acc_h[xi][ct][r] + acc_l[xi][ct][r] * 2.44140625e-4f;
                }
            }
        }
    }
}

// MFMA FC: out[n][co][t] = sum_f w[co][f] * s16[n][t][f]. Output z6 [n][co][300] f32.
template <int FIN, int OUT>
__global__ void __launch_bounds__(256) k_fc_mfma(const _Float16* __restrict__ s16,
                                                 const _Float16* __restrict__ wm,
                                                 float* __restrict__ z) {
    constexpr int NT = 19;
    constexpr int CT = OUT / 16;
    constexpr int KCH = 512;
    constexpr int NK = FIN / KCH;
    __shared__ _Float16 lds[KCH * 16];   // 16 KB

    int bid = blockIdx.x;           // grid = (CT/4) * NBATCH * NT
    int tc = bid % NT;
    int n  = (bid / NT) % NBATCH;
    int cg = bid / (NT * NBATCH);
    int tid = threadIdx.x;
    int lane = tid & 63, wv = tid >> 6;
    int tl = lane & 15, hi = lane >> 4;
    int ct = cg * 4 + wv;

    f32x4 acc_h = (f32x4){0.f, 0.f, 0.f, 0.f};
    f32x4 acc_l = (f32x4){0.f, 0.f, 0.f, 0.f};
    const h8t* wmv = (const h8t*)wm;

    for (int kb = 0; kb < NK; ++kb) {
        __syncthreads();
#pragma unroll
        for (int j = 0; j < 4; ++j) {
            int chunk = tid + j * 256;
            int c = chunk & 63;
            int t = chunk >> 6;
            int tg = tc * 16 + t;
            h8t v;
#pragma unroll
            for (int e = 0; e < 8; ++e) v[e] = (_Float16)0.0f;
            if (tg < TT) v = *(const h8t*)(s16 + ((size_t)(n * TT + tg) * FIN + kb * KCH + c * 8));
            *(h8t*)(lds + ((t * 64 + (c ^ (t & 7))) << 3)) = v;
        }
        __syncthreads();
#pragma unroll
        for (int kc = 0; kc < KCH / 32; ++kc) {
            int c = kc * 4 + hi;
            h8t bf = *(const h8t*)(lds + ((tl * 64 + (c ^ (tl & 7))) << 3));
            size_t wbase = ((size_t)((kb * (KCH / 32) + kc) * CT + ct)) * 2;
            h8t ah = wmv[(wbase + 0) * 64 + lane];
            h8t al = wmv[(wbase + 1) * 64 + lane];
            acc_h = __builtin_amdgcn_mfma_f32_16x16x32_f16(ah, bf, acc_h, 0, 0, 0);
            acc_l = __builtin_amdgcn_mfma_f32_16x16x32_f16(al, bf, acc_l, 0, 0, 0);
        }
    }
    int tg = tc * 16 + tl;
    if (tg < TT) {
#pragma unroll
        for (int r = 0; r < 4; ++r) {
            int co = ct * 16 + hi * 4 + r;
            z[(size_t)(n * OUT + co) * TT + tg] = acc_h[r] + acc_l[r] * 2.44140625e-4f;
        }
    }
}

// FC with packed fp32 FMA over the t dimension (tiny L7 11x256).
template <int OUT, int FIN, int OPER, int FSPLIT>
__global__ void k_fc_a(const float* __restrict__ s, const float* __restrict__ wgt,
                       float* __restrict__ z) {
    constexpr int OG = OUT / OPER, FCH = FIN / FSPLIT;
    int idx = blockIdx.x * 256 + threadIdx.x;
    if (idx >= NBATCH * OG * TC * FSPLIT) return;
    int tc = idx % TC;
    int og = (idx / TC) % OG;
    int n  = (idx / (TC * OG)) % NBATCH;
    int sp = idx / (TC * OG * NBATCH);
    const float* sb = s + (size_t)n * FIN * TT + (size_t)sp * FCH * TT + tc * 4;
    const float* wb = wgt + (size_t)sp * FCH;
    pf2 acc[OPER][2];
#pragma unroll
    for (int k = 0; k < OPER; ++k) { acc[k][0] = (pf2){0.f, 0.f}; acc[k][1] = (pf2){0.f, 0.f}; }
#pragma unroll 2
    for (int f = 0; f < FCH; f += 4) {
        float4 s0 = *(const float4*)(sb + (size_t)(f + 0) * TT);
        float4 s1 = *(const float4*)(sb + (size_t)(f + 1) * TT);
        float4 s2 = *(const float4*)(sb + (size_t)(f + 2) * TT);
        float4 s3 = *(const float4*)(sb + (size_t)(f + 3) * TT);
        pf2 s0a = {s0.x, s0.y}, s0b = {s0.z, s0.w};
        pf2 s1a = {s1.x, s1.y}, s1b = {s1.z, s1.w};
        pf2 s2a = {s2.x, s2.y}, s2b = {s2.z, s2.w};
        pf2 s3a = {s3.x, s3.y}, s3b = {s3.z, s3.w};
#pragma unroll
        for (int k = 0; k < OPER; ++k) {
            float4 wv = *(const float4*)(wb + (size_t)(og * OPER + k) * FIN + f);
            pf2 wx = {wv.x, wv.x}, wy = {wv.y, wv.y}, wz = {wv.z, wv.z}, ww = {wv.w, wv.w};
            pf2 a0 = acc[k][0], a1 = acc[k][1];
            a0 = __builtin_elementwise_fma(wx, s0a, a0);
            a0 = __builtin_elementwise_fma(wy, s1a, a0);
            a0 = __builtin_elementwise_fma(wz, s2a, a0);
            a0 = __builtin_elementwise_fma(ww, s3a, a0);
            a1 = __builtin_elementwise_fma(wx, s0b, a1);
            a1 = __builtin_elementwise_fma(wy, s1b, a1);
            a1 = __builtin_elementwise_fma(wz, s2b, a1);
            a1 = __builtin_elementwise_fma(ww, s3b, a1);
            acc[k][0] = a0; acc[k][1] = a1;
        }
    }
#pragma unroll
    for (int k = 0; k < OPER; ++k) {
        float4 o;
        o.x = acc[k][0].x; o.y = acc[k][0].y; o.z = acc[k][1].x; o.w = acc[k][1].y;
        *(float4*)(z + ((size_t)sp * NBATCH * OUT + (size_t)n * OUT + og * OPER + k) * TT + tc * 4) = o;
    }
}

extern "C" void kernel_launch(void* const* d_in, const int* in_sizes, int n_in,
                              void* d_out, int out_size, void* d_ws, size_t ws_size,
                              hipStream_t stream) {
    const float* s_in = (const float*)d_in[0]; // (4,2,128,128,300)
    const float* w1   = (const float*)d_in[1]; // (32,2,5,5)
    const float* w2   = (const float*)d_in[2]; // (64,32,3,3)
    const float* w3   = (const float*)d_in[3]; // (64,64,3,3)
    const float* w4a  = (const float*)d_in[4]; // (256,4096)
    const float* w4b  = (const float*)d_in[5]; // (11,256)
    float* out = (float*)d_out;                // (4,11,300)

    // Workspace map (floats): Z 39,321,600 | Sb 9,830,400 | WP 56,896.
    // Z: z3 [tc][65536][16] = 19.92M floats at [0..); z5 [tc][16384][16] = 4.98M;
    //    S16 @ Z+25M (2.46M f); wm4 @ Z+28M (1.05M f); wl1m @ Z+30M.
    // Sb: s0 f32 [0..2.46M); s2h f16 @ Sb+2.5M; s4h f16 @ Sb+5M (sequential liveness);
    //     s6 f32 reuses Sb[0..).
    float* Z  = (float*)d_ws;
    float* Sb = Z + 39321600;
    float* WP = Sb + 9830400;
    _Float16* wm2 = (_Float16*)(WP + 1600);
    _Float16* wm3 = (_Float16*)(WP + 1600 + 18432);
    _Float16* S16 = (_Float16*)(Z + 25000000);
    _Float16* wm4 = (_Float16*)(Z + 28000000);
    _Float16* wl1m = (_Float16*)(Z + 30000000);          // 6144 halves
    float* s0 = Sb;                                      // f32 (4,2,32,32,300)
    _Float16* s2h = (_Float16*)(Sb + 2500000);           // f16 [n][4][16][16][300][8]
    _Float16* s4h = (_Float16*)(Sb + 5000000);           // f16 [n][8][8][8][300][8]

    auto g = [](int n) { return (n + 255) / 256; };
    auto g64 = [](int n) { return (n + 63) / 64; };

    // weight packs (independent of activations; Z high region never aliases z3/z5)
    k_pack_wl1<<<3, 256, 0, stream>>>(w1, wl1m);
    k_pack_wmfma<<<g(4608), 256, 0, stream>>>(w2, wm2, 32, 64, 4608);
    k_pack_wmfma<<<g(9216), 256, 0, stream>>>(w3, wm3, 64, 64, 9216);
    k_pack_wfc<<<g(262144), 256, 0, stream>>>(w4a, wm4, 4096, 256, 262144);

    // L0: 4x4 pool + psp -> s0 (4,2,32,32,300) f32 @ Sb
    k_pool4<<<g(614400), 256, 0, stream>>>(s_in, Z);
    k_scan_redp<1><<<g64(8192), 64, 0, stream>>>(Z, s0, 8192, 0);

    // L1 fused v2: conv 5x5 MFMA + psp + pool + psp -> s2h. grid 512 x 256.
    k_l1_fused<<<512, 256, 0, stream>>>(s0, wl1m, s2h);

    // L3 conv 3x3 (32->64, 16x16) MFMA, YPB=2: z3 [tc][p][16] @ Z. grid 19*8*4 = 608.
    k_conv_mfma<32, 64, 16, 16, 2><<<608, 256, 0, stream>>>(s2h, wm2, Z);
    // L3 psp + 2x2 pool + L4 psp -> s4h f16 conv-native. 256 blocks.
    k_spsq16<64, 8, 8><<<256, 256, 0, stream>>>(Z, s4h);

    // L5 conv 3x3 (64->64, 8x8) MFMA, YPB=1: z5 [tc][p][16] @ Z. grid 19*8*4 = 608.
    k_conv_mfma<64, 64, 8, 8, 1><<<608, 256, 0, stream>>>(s4h, wm3, Z);
    // psp scan -> f16 spikes [n][t][f] @ S16 (16384 neurons).
    k_scan16_f16<<<256, 64, 0, stream>>>(Z, S16);

    // L6: fc 4096->256 MFMA: z6 (4,256,300) @ Z. grid = 4 cog * 4 n * 19 tc = 304.
    k_fc_mfma<4096, 256><<<304, 256, 0, stream>>>(S16, wm4, Z);
    k_scan_redp<1><<<g64(1024), 64, 0, stream>>>(Z, Sb, 1024, 0);

    // L7: fc 256->11 + psp -> out
    k_fc_a<11, 256, 1, 1><<<g(3300), 256, 0, stream>>>(Sb, w4b, Z);
    k_scan_redp<1><<<1, 64, 0, stream>>>(Z, out, 44, 0);
}

// Round 8
// 522.985 us; speedup vs baseline: 1.2167x; 1.0436x over previous
//
#include <hip/hip_runtime.h>
#include <cstdint>

#define TT 300   // timesteps
#define TC 75    // TT/4
#define NBATCH 4

typedef float pf2 __attribute__((ext_vector_type(2)));   // packs to v_pk_fma_f32
typedef _Float16 h8t __attribute__((ext_vector_type(8)));  // 4 VGPRs = MFMA f16 A/B frag
typedef float f32x4 __attribute__((ext_vector_type(4)));   // MFMA C/D frag

// PSP + refractory IIR step, exact op order of the reference scan.
__device__ __forceinline__ void psp_step(float z, float& gp, float& hp, float& gr, float& hr, float& s_out) {
    hp = 0.90483741803595957f * (hp + gp);      // a_sr = exp(-1/10)
    gp = 0.90483741803595957f * gp + z;
    hr = 0.36787944117144233f * (hr + gr);      // a_rf = exp(-1)
    gr = 0.36787944117144233f * gr;
    float u = 0.27182818284590452f * hp + (-54.365636569180904f) * hr; // c_sr*hp + c_rf*hr
    float s = (u >= 10.0f) ? 1.0f : 0.0f;
    gr += s;
    s_out = s;
}

// Per-neuron scan over T, 12-step chunks, [p][300] layout (used for L0 and L6).
template <int R>
__global__ void k_scan_redp(const float* __restrict__ z, float* __restrict__ s,
                            int n_neur, int pstride) {
    int i = blockIdx.x * 64 + threadIdx.x;
    if (i >= n_neur) return;
    const float* zp = z + (size_t)i * TT;
    float* sp = s + (size_t)i * TT;
    float gp = 0.f, hp = 0.f, gr = 0.f, hr = 0.f;
#pragma unroll 1
    for (int c = 0; c < 25; ++c) {
        const float* p = zp + c * 12;
        float4 a0 = *(const float4*)(p);
        float4 a1 = *(const float4*)(p + 4);
        float4 a2 = *(const float4*)(p + 8);
#pragma unroll
        for (int r = 1; r < R; ++r) {
            const float* pr = p + (size_t)r * pstride;
            float4 b0 = *(const float4*)(pr);
            float4 b1 = *(const float4*)(pr + 4);
            float4 b2 = *(const float4*)(pr + 8);
            a0.x += b0.x; a0.y += b0.y; a0.z += b0.z; a0.w += b0.w;
            a1.x += b1.x; a1.y += b1.y; a1.z += b1.z; a1.w += b1.w;
            a2.x += b2.x; a2.y += b2.y; a2.z += b2.z; a2.w += b2.w;
        }
        float4 o0, o1, o2;
        psp_step(a0.x, gp, hp, gr, hr, o0.x);
        psp_step(a0.y, gp, hp, gr, hr, o0.y);
        psp_step(a0.z, gp, hp, gr, hr, o0.z);
        psp_step(a0.w, gp, hp, gr, hr, o0.w);
        psp_step(a1.x, gp, hp, gr, hr, o1.x);
        psp_step(a1.y, gp, hp, gr, hr, o1.y);
        psp_step(a1.z, gp, hp, gr, hr, o1.z);
        psp_step(a1.w, gp, hp, gr, hr, o1.w);
        psp_step(a2.x, gp, hp, gr, hr, o2.x);
        psp_step(a2.y, gp, hp, gr, hr, o2.y);
        psp_step(a2.z, gp, hp, gr, hr, o2.z);
        psp_step(a2.w, gp, hp, gr, hr, o2.w);
        float* q = sp + c * 12;
        *(float4*)(q) = o0;
        *(float4*)(q + 4) = o1;
        *(float4*)(q + 8) = o2;
    }
}

// Scan for L5 output: reads z5 in [tc][p][16] layout (p = n*4096 + f), writes f16
// spikes S16 [n][t][4096]. Wave reads are 64 lanes x 64B contiguous = 4KB segments.
__global__ void k_scan16_f16(const float* __restrict__ z, _Float16* __restrict__ s16) {
    int i = blockIdx.x * 64 + threadIdx.x;     // 16384 neurons, grid 256 x 64
    int n = i >> 12, f = i & 4095;
    const float* zp = z + (size_t)i * 16;
    _Float16* sp = s16 + ((size_t)n * TT) * 4096 + f;
    float gp = 0.f, hp = 0.f, gr = 0.f, hr = 0.f;
#define SC16_CHUNK(TCI, NTT) do {                                              \
    const float* pp = zp + (size_t)(TCI) * (16384 * 16);                       \
    float4 a0 = *(const float4*)(pp);                                          \
    float4 a1 = *(const float4*)(pp + 4);                                      \
    float4 a2 = *(const float4*)(pp + 8);                                      \
    float4 a3 = *(const float4*)(pp + 12);                                     \
    float zv[16] = {a0.x,a0.y,a0.z,a0.w,a1.x,a1.y,a1.z,a1.w,                   \
                    a2.x,a2.y,a2.z,a2.w,a3.x,a3.y,a3.z,a3.w};                  \
    _Pragma("unroll")                                                          \
    for (int tt = 0; tt < (NTT); ++tt) {                                       \
        float o;                                                               \
        psp_step(zv[tt], gp, hp, gr, hr, o);                                   \
        sp[(size_t)((TCI) * 16 + tt) * 4096] = (_Float16)o;                    \
    }                                                                          \
} while (0)
#pragma unroll 1
    for (int tcc = 0; tcc < 18; ++tcc) SC16_CHUNK(tcc, 16);
    SC16_CHUNK(18, 12);
#undef SC16_CHUNK
}

// Fused scan-pool-scan for L3 output: reads z3 [tc][p][16] (p = ((n*C+c)*H+y)*W+x),
// emits f16 spikes conv-native [n][c/8][y2][x2][t][8].
template <int C, int H2, int W2>
__global__ void __launch_bounds__(256) k_spsq16(const float* __restrict__ z,
                                                _Float16* __restrict__ s16) {
    constexpr int H = 2 * H2, W = 2 * W2;
    constexpr int NP = NBATCH * C * H * W;
    constexpr int C8 = C / 8;
    __shared__ _Float16 tile[16 * C];

    int i = blockIdx.x * 256 + threadIdx.x;    // grid exact: N*C*H2*W2*4 threads
    int q = i & 3;
    int p = i >> 2;
    int c  = p % C;
    int x2 = (p / C) % W2;
    int y2 = (p / (C * W2)) % H2;
    int n  = p / (C * W2 * H2);
    int dy = q >> 1, dx = q & 1;
    int pz = ((n * C + c) * H + 2 * y2 + dy) * W + 2 * x2 + dx;
    const float* zp = z + (size_t)pz * 16;

    int tid = threadIdx.x;
    int wt  = tid & 15;
    int wc8 = tid >> 4;
    int p0 = blockIdx.x * 64;                  // block's site (C-aligned p)
    int wx2 = (p0 / C) % W2;
    int wy2 = (p0 / (C * W2)) % H2;
    int wn  = p0 / (C * W2 * H2);
    _Float16* wbase = s16 + ((((size_t)(wn * C8 + wc8) * H2 + wy2) * W2 + wx2) * TT) * 8;

    float gp = 0.f, hp = 0.f, gr = 0.f, hr = 0.f;   // conv neuron IIR
    float Gp = 0.f, Hp = 0.f, Gr = 0.f, Hr = 0.f;   // pooled neuron IIR
#define SPSQ_CHUNK(TCI, NTT) do {                                              \
    const float* pp = zp + (size_t)(TCI) * (NP * 16);                          \
    float4 a0 = *(const float4*)(pp);                                          \
    float4 a1 = *(const float4*)(pp + 4);                                      \
    float4 a2 = *(const float4*)(pp + 8);                                      \
    float4 a3 = *(const float4*)(pp + 12);                                     \
    float zv[16] = {a0.x,a0.y,a0.z,a0.w,a1.x,a1.y,a1.z,a1.w,                   \
                    a2.x,a2.y,a2.z,a2.w,a3.x,a3.y,a3.z,a3.w};                  \
    float ov[16];                                                              \
    _Pragma("unroll")                                                          \
    for (int tt = 0; tt < (NTT); ++tt) {                                       \
        float sq;                                                              \
        psp_step(zv[tt], gp, hp, gr, hr, sq);                                  \
        float t1 = sq + __shfl_xor(sq, 1, 64);                                 \
        float pool = t1 + __shfl_xor(t1, 2, 64);                               \
        psp_step(11.0f * pool, Gp, Hp, Gr, Hr, ov[tt]);                        \
    }                                                                          \
    __syncthreads();                                                           \
    if (q == 0) {                                                              \
        _Pragma("unroll")                                                      \
        for (int tt = 0; tt < (NTT); ++tt)                                     \
            tile[tt * C + c] = (_Float16)ov[tt];                               \
    }                                                                          \
    __syncthreads();                                                           \
    if (tid < 16 * C8 && wt < (NTT)) {                                         \
        h8t v = *(const h8t*)(tile + wt * C + wc8 * 8);                        \
        *(h8t*)(wbase + (size_t)((TCI) * 16 + wt) * 8) = v;                    \
    }                                                                          \
} while (0)
#pragma unroll 1
    for (int tcc = 0; tcc < 18; ++tcc) SPSQ_CHUNK(tcc, 16);
    SPSQ_CHUNK(18, 12);
#undef SPSQ_CHUNK
}

// Pack 3x3 OIHW conv weights into MFMA A-fragments with f16 hi/lo split.
// Layout: [tap 9][kc CIN/32][ct COUT/16][ver 2][lane 64][j 8] halves.
__global__ void k_pack_wmfma(const float* __restrict__ w, _Float16* __restrict__ wm,
                             int CIN, int COUT, int total) {
    int i = blockIdx.x * 256 + threadIdx.x;
    if (i >= total) return;
    int lane = i & 63;
    int r = i >> 6;
    int ver = r & 1; r >>= 1;
    int KC = CIN >> 5, CT = COUT >> 4;
    int ct = r % CT; r /= CT;
    int kc = r % KC;
    int tap = r / KC;
    int ky = tap / 3, kx = tap % 3;
    int co  = ct * 16 + (lane & 15);
    int ci0 = kc * 32 + (lane >> 4) * 8;
    _Float16 out[8];
#pragma unroll
    for (int j = 0; j < 8; ++j) {
        float wf = w[((co * CIN + ci0 + j) * 3 + ky) * 3 + kx];
        _Float16 hi = (_Float16)wf;
        out[j] = ver ? (_Float16)((wf - (float)hi) * 4096.0f) : hi;
    }
    *(h8t*)(wm + (size_t)i * 8) = *(h8t*)out;
}

// Pack FC weights (COUT, FIN) row-major into MFMA A-fragments, hi/lo split.
__global__ void k_pack_wfc(const float* __restrict__ w, _Float16* __restrict__ wm,
                           int FIN, int COUT, int total) {
    int i = blockIdx.x * 256 + threadIdx.x;
    if (i >= total) return;
    int lane = i & 63;
    int r = i >> 6;
    int ver = r & 1; r >>= 1;
    int CT = COUT >> 4;
    int ct = r % CT;
    int kg = r / CT;
    int co = ct * 16 + (lane & 15);
    int f0 = kg * 32 + (lane >> 4) * 8;
    _Float16 out[8];
#pragma unroll
    for (int j = 0; j < 8; ++j) {
        float wf = w[(size_t)co * FIN + f0 + j];
        _Float16 hi = (_Float16)wf;
        out[j] = ver ? (_Float16)((wf - (float)hi) * 4096.0f) : hi;
    }
    *(h8t*)(wm + (size_t)i * 8) = *(h8t*)out;
}

// Pack L1 5x5 (32,2,5,5) weights into padded-K MFMA A-frags, hi/lo split.
// K = 96: k -> ky = k>>4, slot = k&15, kx = slot>>1, ci = slot&1; pad slots zero.
__global__ void k_pack_wl1(const float* __restrict__ w, _Float16* __restrict__ wm) {
    int i = blockIdx.x * 256 + threadIdx.x;
    if (i >= 768) return;
    int lane = i & 63;
    int r = i >> 6;
    int ver = r & 1;
    int ch = (r >> 1) & 1;
    int kc = r >> 2;
    int co = ch * 16 + (lane & 15);
    int k0 = kc * 32 + (lane >> 4) * 8;
    _Float16 out[8];
#pragma unroll
    for (int j = 0; j < 8; ++j) {
        int k = k0 + j;
        int ky = k >> 4, slot = k & 15, kx = slot >> 1, ci = slot & 1;
        float wf = (ky < 5 && kx < 5) ? w[((co * 2 + ci) * 5 + ky) * 5 + kx] : 0.f;
        _Float16 hif = (_Float16)wf;
        out[j] = ver ? (_Float16)((wf - (float)hif) * 4096.0f) : hif;
    }
    *(h8t*)(wm + (size_t)i * 8) = *(h8t*)out;
}

// 4x4 sum-pool * 11.0 over (N,2,128,128,T) -> z (N,2,32,32,T). Thread = (p, tc), tc fastest.
__global__ void k_pool4(const float* __restrict__ x, float* __restrict__ z) {
    int idx = blockIdx.x * 256 + threadIdx.x;
    if (idx >= NBATCH * 2 * 32 * 32 * TC) return;
    int tc = idx % TC;
    int p  = idx / TC;
    int w  = p % 32;
    int h  = (p / 32) % 32;
    int nc = p / (32 * 32);
    const float* base = x + (((size_t)nc * 128 + h * 4) * 128 + w * 4) * TT + tc * 4;
    float ax = 0.f, ay = 0.f, az = 0.f, aw = 0.f;
#pragma unroll
    for (int i = 0; i < 4; ++i)
#pragma unroll
        for (int j = 0; j < 4; ++j) {
            float4 v = *(const float4*)(base + ((size_t)i * 128 + j) * TT);
            ax += v.x; ay += v.y; az += v.z; aw += v.w;
        }
    float4 o; o.x = 11.0f * ax; o.y = 11.0f * ay; o.z = 11.0f * az; o.w = 11.0f * aw;
    *(float4*)(z + (size_t)p * TT + tc * 4) = o;
}

// Fused L1 (v2): 5x5 conv (2->32) MFMA + psp + 2x2 pool + psp -> s2h f16 conv-native.
// Block = (n, ch co-half, xh x-octet, y2 pool-row) owns ALL 300 t (IIR in VGPRs).
// Proven round-7 config: 42-half stage stride (odd-word, conflict-free) + T14 async
// staging + 3 barriers/tile + weights in regs. 546 us total, L1 ~70 us.
__global__ void __launch_bounds__(256) k_l1_fused(const float* __restrict__ s0,
                                                  const _Float16* __restrict__ wl1,
                                                  _Float16* __restrict__ s2h) {
    constexpr int NT = 19;
    __shared__ _Float16 stage[7 * 16 * 42];   // [row7][t16][42: 16lx x 2ci + 10 pad]
    __shared__ float    trans[256 * 17];      // [neuron 256][16 t + 1 pad]
    __shared__ _Float16 tile[4 * 16 * 16];    // [x2l][t][co]

    int bid = blockIdx.x;                     // grid 512 = n4 * ch2 * xh4 * y2_16
    int y2 = bid & 15;
    int xh = (bid >> 4) & 3;
    int ch = (bid >> 6) & 1;
    int n  = bid >> 7;
    int tid = threadIdx.x;
    int lane = tid & 63;
    int wv = tid >> 6;          // 4 waves: (yy, xq)
    int tl = lane & 15;
    int hi = lane >> 4;
    int yy = wv >> 1;
    int xq = wv & 1;

    int q    = tid & 3;         // scan role: dy=q>>1, dx=q&1 (lane bits 0-1 -> shfl pool)
    int co_s = (tid >> 2) & 15;
    int x2l_s = tid >> 6;
    int wt  = tid & 15;         // writer role (tid<128)
    int wc8 = (tid >> 4) & 1;
    int wx  = tid >> 5;

    // per-thread stage geometry: 4 items, item i = (r, ci, lx, tq); t = tq*4+e.
    bool   it_v[4];
    size_t it_off[4];
    int    it_adr[4];
    int    it_tq[4];
#pragma unroll
    for (int ii = 0; ii < 4; ++ii) {
        int i = tid + ii * 256;
        int tq = i & 3;
        int lx = (i >> 2) & 15;
        int ci = (i >> 6) & 1;
        int r  = i >> 7;
        int gx = xh * 8 + lx - 2;
        int gy = y2 * 2 + r - 2;
        bool sp = (i < 896) && gx >= 0 && gx < 32 && gy >= 0 && gy < 32;
        it_v[ii]   = sp;
        it_off[ii] = sp ? ((((size_t)(n * 2 + ci) * 32 + gy) * 32 + gx) * TT + tq * 4) : 0;
        it_adr[ii] = (r * 16 + tq * 4) * 42 + lx * 2 + ci;
        it_tq[ii]  = tq;
    }

    const h8t* wv4 = (const h8t*)wl1;
    h8t wfr[3][2];
#pragma unroll
    for (int kc = 0; kc < 3; ++kc) {
        wfr[kc][0] = wv4[((kc * 2 + ch) * 2 + 0) * 64 + lane];
        wfr[kc][1] = wv4[((kc * 2 + ch) * 2 + 1) * 64 + lane];
    }

    float gp = 0.f, hp = 0.f, gr = 0.f, hr = 0.f;
    float Gp = 0.f, Hp = 0.f, Gr = 0.f, Hr = 0.f;

    float4 pf[4];
#pragma unroll
    for (int ii = 0; ii < 4; ++ii) {
        pf[ii] = make_float4(0.f, 0.f, 0.f, 0.f);
        if (it_v[ii]) pf[ii] = *(const float4*)(s0 + it_off[ii]);
    }

#pragma unroll 1
    for (int tc = 0; tc < NT; ++tc) {
#pragma unroll
        for (int ii = 0; ii < 4; ++ii) {
            if (tid + ii * 256 < 896) {
                stage[it_adr[ii] + 0 * 42] = (_Float16)pf[ii].x;
                stage[it_adr[ii] + 1 * 42] = (_Float16)pf[ii].y;
                stage[it_adr[ii] + 2 * 42] = (_Float16)pf[ii].z;
                stage[it_adr[ii] + 3 * 42] = (_Float16)pf[ii].w;
            }
        }
        if (tc + 1 < NT) {
#pragma unroll
            for (int ii = 0; ii < 4; ++ii) {
                float4 v = make_float4(0.f, 0.f, 0.f, 0.f);
                if (it_v[ii] && (tc + 1) * 16 + it_tq[ii] * 4 + 3 < TT)
                    v = *(const float4*)(s0 + it_off[ii] + (tc + 1) * 16);
                pf[ii] = v;
            }
        }
        __syncthreads();   // [B] stage ready
        f32x4 ah4[4], al4[4];
#pragma unroll
        for (int xi = 0; xi < 4; ++xi) { ah4[xi] = (f32x4){0.f,0.f,0.f,0.f}; al4[xi] = (f32x4){0.f,0.f,0.f,0.f}; }
#pragma unroll
        for (int kc = 0; kc < 3; ++kc) {
            int row = yy + 2 * kc + (hi >> 1);
#pragma unroll
            for (int xi = 0; xi < 4; ++xi) {
                int xo = xq * 4 + xi;
                const uint32_t* lp = (const uint32_t*)(stage + (row * 16 + tl) * 42 + xo * 2 + (hi & 1) * 8);
                union { uint32_t u[4]; h8t h; } bu;
                bu.u[0] = lp[0]; bu.u[1] = lp[1]; bu.u[2] = lp[2]; bu.u[3] = lp[3];
                ah4[xi] = __builtin_amdgcn_mfma_f32_16x16x32_f16(wfr[kc][0], bu.h, ah4[xi], 0, 0, 0);
                al4[xi] = __builtin_amdgcn_mfma_f32_16x16x32_f16(wfr[kc][1], bu.h, al4[xi], 0, 0, 0);
            }
        }
#pragma unroll
        for (int xi = 0; xi < 4; ++xi) {
            int xo = xq * 4 + xi;
#pragma unroll
            for (int r = 0; r < 4; ++r) {
                float u = ah4[xi][r] + al4[xi][r] * 2.44140625e-4f;
                int rowt = ((xo >> 1) * 16 + hi * 4 + r) * 4 + yy * 2 + (xo & 1);
                trans[rowt * 17 + tl] = u;
            }
        }
        __syncthreads();   // [C] trans ready
#pragma unroll
        for (int t = 0; t < 16; ++t) {
            float u = trans[tid * 17 + t];
            float sq;
            psp_step(u, gp, hp, gr, hr, sq);
            float t1 = sq + __shfl_xor(sq, 1, 64);
            float pool = t1 + __shfl_xor(t1, 2, 64);
            float ov;
            psp_step(11.0f * pool, Gp, Hp, Gr, Hr, ov);
            if (q == 0) tile[(x2l_s * 16 + t) * 16 + co_s] = (_Float16)ov;
        }
        __syncthreads();   // [D] tile ready
        if (tid < 128) {
            int tg = tc * 16 + wt;
            if (tg < TT) {
                h8t v = *(const h8t*)(tile + (wx * 16 + wt) * 16 + wc8 * 8);
                int cg8 = ch * 2 + wc8;
                int x2g = xh * 4 + wx;
                *(h8t*)(s2h + ((((size_t)(n * 4 + cg8) * 16 + y2) * 16 + x2g) * (size_t)TT + tg) * 8) = v;
            }
        }
    }
}

// MFMA 3x3 conv (pad 1). Input: f16 spikes [n][ci/8][y][x][t][8]. Output z in
// [tc][p][16] layout. XSPL x-split doubles the grid for occupancy; launch_bounds
// stays (256,2) — round-4's (256,4) forced 64-VGPR acc spill (FETCH+WRITE blowup).
// With XSPL=2 the acc block halves (64 regs) so compiler lands ~100 VGPR and the
// HW reaches 4 blocks/CU via LDS(<=40KB)/VGPR(<=128) limits naturally.
template <int CIN, int COUT, int H, int W, int YPB, int XSPL>
__global__ void __launch_bounds__(256, 2) k_conv_mfma(const _Float16* __restrict__ s16,
                                                      const _Float16* __restrict__ wm,
                                                      float* __restrict__ z) {
    constexpr int NT = 19;          // ceil(300/16)
    constexpr int KC = CIN / 32;
    constexpr int CH = CIN / 8;
    constexpr int XW = W / XSPL;    // output x per block (even -> line ownership kept)
    constexpr int XL = XW + 2;
    constexpr int CT = COUT / 16;
    constexpr int XPW = XW / 4;
    constexpr int ROWS = YPB + 2;
    constexpr int NP = NBATCH * COUT * H * W;
    __shared__ _Float16 lds[ROWS * XL * 16 * CIN];

    int bid = blockIdx.x;
    int tc = bid % NT;
    int r0 = bid / NT;
    int yb = (r0 % (H / YPB)) * YPB;
    r0 /= (H / YPB);
    int xh = r0 % XSPL;
    int n  = r0 / XSPL;
    int xb = xh * XW;
    int tid = threadIdx.x;

    constexpr int TOT = ROWS * XL * CH * 16;
    for (int i = tid; i < TOT; i += 256) {
        int t   = i & 15;
        int c   = (i >> 4) % CH;
        int xc  = ((i >> 4) / CH) % XL;
        int row = ((i >> 4) / CH) / XL;
        int tg = tc * 16 + t;
        int xi = xb + xc - 1;
        int yi = yb + row - 1;
        h8t v;
#pragma unroll
        for (int e = 0; e < 8; ++e) v[e] = (_Float16)0.0f;
        if (xi >= 0 && xi < W && yi >= 0 && yi < H && tg < TT)
            v = *(const h8t*)(s16 + ((((size_t)(n * CH + c) * H + yi) * W + xi) * TT + tg) * 8);
        int swz = (CIN == 32) ? ((t >> 1) & 3) : (t & 7);
        int off = ((row * XL + xc) * 16 + t) * CIN + ((c ^ swz) << 3);
        *(h8t*)(lds + off) = v;
    }
    __syncthreads();

    int lane = tid & 63;
    int wv   = tid >> 6;
    int tl   = lane & 15;
    int hi   = lane >> 4;
    const h8t* wmv = (const h8t*)wm;
    int swz = (CIN == 32) ? ((tl >> 1) & 3) : (tl & 7);

#pragma unroll
    for (int yy = 0; yy < YPB; ++yy) {
        f32x4 acc_h[XPW][CT], acc_l[XPW][CT];
#pragma unroll
        for (int a = 0; a < XPW; ++a)
#pragma unroll
            for (int b = 0; b < CT; ++b) {
                acc_h[a][b] = (f32x4){0.f, 0.f, 0.f, 0.f};
                acc_l[a][b] = (f32x4){0.f, 0.f, 0.f, 0.f};
            }
#pragma unroll
        for (int ky = 0; ky < 3; ++ky) {
#pragma unroll
            for (int kx = 0; kx < 3; ++kx) {
                int tap = ky * 3 + kx;
#pragma unroll
                for (int kc = 0; kc < KC; ++kc) {
                    h8t bf[XPW];
#pragma unroll
                    for (int xi = 0; xi < XPW; ++xi) {
                        int x = wv * XPW + xi;
                        int c = kc * 4 + hi;
                        int off = (((yy + ky) * XL + (x + kx)) * 16 + tl) * CIN + ((c ^ swz) << 3);
                        bf[xi] = *(const h8t*)(lds + off);
                    }
#pragma unroll
                    for (int ct = 0; ct < CT; ++ct) {
                        size_t wbase = ((size_t)(tap * KC + kc) * CT + ct) * 2;
                        h8t ah = wmv[(wbase + 0) * 64 + lane];
                        h8t al = wmv[(wbase + 1) * 64 + lane];
#pragma unroll
                        for (int xi = 0; xi < XPW; ++xi) {
                            acc_h[xi][ct] = __builtin_amdgcn_mfma_f32_16x16x32_f16(ah, bf[xi], acc_h[xi][ct], 0, 0, 0);
                            acc_l[xi][ct] = __builtin_amdgcn_mfma_f32_16x16x32_f16(al, bf[xi], acc_l[xi][ct], 0, 0, 0);
                        }
                    }
                }
            }
        }
        // C/D layout: col = lane&15 (= t), row = (lane>>4)*4 + r (= cout)
#pragma unroll
        for (int xi = 0; xi < XPW; ++xi) {
            int x = xb + wv * XPW + xi;
#pragma unroll
            for (int ct = 0; ct < CT; ++ct) {
#pragma unroll
                for (int r = 0; r < 4; ++r) {
                    int co = ct * 16 + hi * 4 + r;
                    int pz = ((n * COUT + co) * H + (yb + yy)) * W + x;
                    z[((size_t)tc * NP + pz) * 16 + tl]
                        = acc_h[xi][ct][r] + acc_l[xi][ct][r] * 2.44140625e-4f;
                }
            }
        }
    }
}

// MFMA FC: out[n][co][t] = sum_f w[co][f] * s16[n][t][f]. Output z6 [n][co][300] f32.
template <int FIN, int OUT>
__global__ void __launch_bounds__(256) k_fc_mfma(const _Float16* __restrict__ s16,
                                                 const _Float16* __restrict__ wm,
                                                 float* __restrict__ z) {
    constexpr int NT = 19;
    constexpr int CT = OUT / 16;
    constexpr int KCH = 512;
    constexpr int NK = FIN / KCH;
    __shared__ _Float16 lds[KCH * 16];   // 16 KB

    int bid = blockIdx.x;           // grid = (CT/4) * NBATCH * NT
    int tc = bid % NT;
    int n  = (bid / NT) % NBATCH;
    int cg = bid / (NT * NBATCH);
    int tid = threadIdx.x;
    int lane = tid & 63, wv = tid >> 6;
    int tl = lane & 15, hi = lane >> 4;
    int ct = cg * 4 + wv;

    f32x4 acc_h = (f32x4){0.f, 0.f, 0.f, 0.f};
    f32x4 acc_l = (f32x4){0.f, 0.f, 0.f, 0.f};
    const h8t* wmv = (const h8t*)wm;

    for (int kb = 0; kb < NK; ++kb) {
        __syncthreads();
#pragma unroll
        for (int j = 0; j < 4; ++j) {
            int chunk = tid + j * 256;
            int c = chunk & 63;
            int t = chunk >> 6;
            int tg = tc * 16 + t;
            h8t v;
#pragma unroll
            for (int e = 0; e < 8; ++e) v[e] = (_Float16)0.0f;
            if (tg < TT) v = *(const h8t*)(s16 + ((size_t)(n * TT + tg) * FIN + kb * KCH + c * 8));
            *(h8t*)(lds + ((t * 64 + (c ^ (t & 7))) << 3)) = v;
        }
        __syncthreads();
#pragma unroll
        for (int kc = 0; kc < KCH / 32; ++kc) {
            int c = kc * 4 + hi;
            h8t bf = *(const h8t*)(lds + ((tl * 64 + (c ^ (tl & 7))) << 3));
            size_t wbase = ((size_t)((kb * (KCH / 32) + kc) * CT + ct)) * 2;
            h8t ah = wmv[(wbase + 0) * 64 + lane];
            h8t al = wmv[(wbase + 1) * 64 + lane];
            acc_h = __builtin_amdgcn_mfma_f32_16x16x32_f16(ah, bf, acc_h, 0, 0, 0);
            acc_l = __builtin_amdgcn_mfma_f32_16x16x32_f16(al, bf, acc_l, 0, 0, 0);
        }
    }
    int tg = tc * 16 + tl;
    if (tg < TT) {
#pragma unroll
        for (int r = 0; r < 4; ++r) {
            int co = ct * 16 + hi * 4 + r;
            z[(size_t)(n * OUT + co) * TT + tg] = acc_h[r] + acc_l[r] * 2.44140625e-4f;
        }
    }
}

// FC with packed fp32 FMA over the t dimension (tiny L7 11x256).
template <int OUT, int FIN, int OPER, int FSPLIT>
__global__ void k_fc_a(const float* __restrict__ s, const float* __restrict__ wgt,
                       float* __restrict__ z) {
    constexpr int OG = OUT / OPER, FCH = FIN / FSPLIT;
    int idx = blockIdx.x * 256 + threadIdx.x;
    if (idx >= NBATCH * OG * TC * FSPLIT) return;
    int tc = idx % TC;
    int og = (idx / TC) % OG;
    int n  = (idx / (TC * OG)) % NBATCH;
    int sp = idx / (TC * OG * NBATCH);
    const float* sb = s + (size_t)n * FIN * TT + (size_t)sp * FCH * TT + tc * 4;
    const float* wb = wgt + (size_t)sp * FCH;
    pf2 acc[OPER][2];
#pragma unroll
    for (int k = 0; k < OPER; ++k) { acc[k][0] = (pf2){0.f, 0.f}; acc[k][1] = (pf2){0.f, 0.f}; }
#pragma unroll 2
    for (int f = 0; f < FCH; f += 4) {
        float4 s0 = *(const float4*)(sb + (size_t)(f + 0) * TT);
        float4 s1 = *(const float4*)(sb + (size_t)(f + 1) * TT);
        float4 s2 = *(const float4*)(sb + (size_t)(f + 2) * TT);
        float4 s3 = *(const float4*)(sb + (size_t)(f + 3) * TT);
        pf2 s0a = {s0.x, s0.y}, s0b = {s0.z, s0.w};
        pf2 s1a = {s1.x, s1.y}, s1b = {s1.z, s1.w};
        pf2 s2a = {s2.x, s2.y}, s2b = {s2.z, s2.w};
        pf2 s3a = {s3.x, s3.y}, s3b = {s3.z, s3.w};
#pragma unroll
        for (int k = 0; k < OPER; ++k) {
            float4 wv = *(const float4*)(wb + (size_t)(og * OPER + k) * FIN + f);
            pf2 wx = {wv.x, wv.x}, wy = {wv.y, wv.y}, wz = {wv.z, wv.z}, ww = {wv.w, wv.w};
            pf2 a0 = acc[k][0], a1 = acc[k][1];
            a0 = __builtin_elementwise_fma(wx, s0a, a0);
            a0 = __builtin_elementwise_fma(wy, s1a, a0);
            a0 = __builtin_elementwise_fma(wz, s2a, a0);
            a0 = __builtin_elementwise_fma(ww, s3a, a0);
            a1 = __builtin_elementwise_fma(wx, s0b, a1);
            a1 = __builtin_elementwise_fma(wy, s1b, a1);
            a1 = __builtin_elementwise_fma(wz, s2b, a1);
            a1 = __builtin_elementwise_fma(ww, s3b, a1);
            acc[k][0] = a0; acc[k][1] = a1;
        }
    }
#pragma unroll
    for (int k = 0; k < OPER; ++k) {
        float4 o;
        o.x = acc[k][0].x; o.y = acc[k][0].y; o.z = acc[k][1].x; o.w = acc[k][1].y;
        *(float4*)(z + ((size_t)sp * NBATCH * OUT + (size_t)n * OUT + og * OPER + k) * TT + tc * 4) = o;
    }
}

extern "C" void kernel_launch(void* const* d_in, const int* in_sizes, int n_in,
                              void* d_out, int out_size, void* d_ws, size_t ws_size,
                              hipStream_t stream) {
    const float* s_in = (const float*)d_in[0]; // (4,2,128,128,300)
    const float* w1   = (const float*)d_in[1]; // (32,2,5,5)
    const float* w2   = (const float*)d_in[2]; // (64,32,3,3)
    const float* w3   = (const float*)d_in[3]; // (64,64,3,3)
    const float* w4a  = (const float*)d_in[4]; // (256,4096)
    const float* w4b  = (const float*)d_in[5]; // (11,256)
    float* out = (float*)d_out;                // (4,11,300)

    // Workspace map (floats): Z 39,321,600 | Sb 9,830,400 | WP 56,896.
    // Z: z3 [tc][65536][16] = 19.92M floats at [0..); z5 [tc][16384][16] = 4.98M;
    //    S16 @ Z+25M (2.46M f); wm4 @ Z+28M (1.05M f); wl1m @ Z+30M.
    // Sb: s0 f32 [0..2.46M); s2h f16 @ Sb+2.5M; s4h f16 @ Sb+5M (sequential liveness);
    //     s6 f32 reuses Sb[0..).
    float* Z  = (float*)d_ws;
    float* Sb = Z + 39321600;
    float* WP = Sb + 9830400;
    _Float16* wm2 = (_Float16*)(WP + 1600);
    _Float16* wm3 = (_Float16*)(WP + 1600 + 18432);
    _Float16* S16 = (_Float16*)(Z + 25000000);
    _Float16* wm4 = (_Float16*)(Z + 28000000);
    _Float16* wl1m = (_Float16*)(Z + 30000000);          // 6144 halves
    float* s0 = Sb;                                      // f32 (4,2,32,32,300)
    _Float16* s2h = (_Float16*)(Sb + 2500000);           // f16 [n][4][16][16][300][8]
    _Float16* s4h = (_Float16*)(Sb + 5000000);           // f16 [n][8][8][8][300][8]

    auto g = [](int n) { return (n + 255) / 256; };
    auto g64 = [](int n) { return (n + 63) / 64; };

    // weight packs (independent of activations; Z high region never aliases z3/z5)
    k_pack_wl1<<<3, 256, 0, stream>>>(w1, wl1m);
    k_pack_wmfma<<<g(4608), 256, 0, stream>>>(w2, wm2, 32, 64, 4608);
    k_pack_wmfma<<<g(9216), 256, 0, stream>>>(w3, wm3, 64, 64, 9216);
    k_pack_wfc<<<g(262144), 256, 0, stream>>>(w4a, wm4, 4096, 256, 262144);

    // L0: 4x4 pool + psp -> s0 (4,2,32,32,300) f32 @ Sb
    k_pool4<<<g(614400), 256, 0, stream>>>(s_in, Z);
    k_scan_redp<1><<<g64(8192), 64, 0, stream>>>(Z, s0, 8192, 0);

    // L1 fused v2: conv 5x5 MFMA + psp + pool + psp -> s2h. grid 512 x 256.
    k_l1_fused<<<512, 256, 0, stream>>>(s0, wl1m, s2h);

    // L3 conv 3x3 (32->64, 16x16) MFMA, YPB=2 XSPL=2: z3 [tc][p][16] @ Z.
    // grid 19*8*2*4 = 1216; LDS 40KB; (256,2) — no forced 4-wave cap (round-4 spill).
    k_conv_mfma<32, 64, 16, 16, 2, 2><<<1216, 256, 0, stream>>>(s2h, wm2, Z);
    // L3 psp + 2x2 pool + L4 psp -> s4h f16 conv-native. 256 blocks.
    k_spsq16<64, 8, 8><<<256, 256, 0, stream>>>(Z, s4h);

    // L5 conv 3x3 (64->64, 8x8) MFMA, YPB=1 XSPL=2: z5 [tc][p][16] @ Z.
    // grid 19*8*2*4 = 1216; LDS 36KB.
    k_conv_mfma<64, 64, 8, 8, 1, 2><<<1216, 256, 0, stream>>>(s4h, wm3, Z);
    // psp scan -> f16 spikes [n][t][f] @ S16 (16384 neurons).
    k_scan16_f16<<<256, 64, 0, stream>>>(Z, S16);

    // L6: fc 4096->256 MFMA: z6 (4,256,300) @ Z. grid = 4 cog * 4 n * 19 tc = 304.
    k_fc_mfma<4096, 256><<<304, 256, 0, stream>>>(S16, wm4, Z);
    k_scan_redp<1><<<g64(1024), 64, 0, stream>>>(Z, Sb, 1024, 0);

    // L7: fc 256->11 + psp -> out
    k_fc_a<11, 256, 1, 1><<<g(3300), 256, 0, stream>>>(Sb, w4b, Z);
    k_scan_redp<1><<<1, 64, 0, stream>>>(Z, out, 44, 0);
}

// Round 9
// 518.434 us; speedup vs baseline: 1.2274x; 1.0088x over previous
//
#include <hip/hip_runtime.h>
#include <cstdint>

#define TT 300   // timesteps
#define TC 75    // TT/4
#define NBATCH 4

typedef float pf2 __attribute__((ext_vector_type(2)));   // packs to v_pk_fma_f32
typedef _Float16 h8t __attribute__((ext_vector_type(8)));  // 4 VGPRs = MFMA f16 A/B frag
typedef float f32x4 __attribute__((ext_vector_type(4)));   // MFMA C/D frag

// PSP + refractory IIR step, exact op order of the reference scan.
__device__ __forceinline__ void psp_step(float z, float& gp, float& hp, float& gr, float& hr, float& s_out) {
    hp = 0.90483741803595957f * (hp + gp);      // a_sr = exp(-1/10)
    gp = 0.90483741803595957f * gp + z;
    hr = 0.36787944117144233f * (hr + gr);      // a_rf = exp(-1)
    gr = 0.36787944117144233f * gr;
    float u = 0.27182818284590452f * hp + (-54.365636569180904f) * hr; // c_sr*hp + c_rf*hr
    float s = (u >= 10.0f) ? 1.0f : 0.0f;
    gr += s;
    s_out = s;
}

// Per-neuron scan over T, 12-step chunks, [p][300] layout (used for L0 and L6).
template <int R>
__global__ void k_scan_redp(const float* __restrict__ z, float* __restrict__ s,
                            int n_neur, int pstride) {
    int i = blockIdx.x * 64 + threadIdx.x;
    if (i >= n_neur) return;
    const float* zp = z + (size_t)i * TT;
    float* sp = s + (size_t)i * TT;
    float gp = 0.f, hp = 0.f, gr = 0.f, hr = 0.f;
#pragma unroll 1
    for (int c = 0; c < 25; ++c) {
        const float* p = zp + c * 12;
        float4 a0 = *(const float4*)(p);
        float4 a1 = *(const float4*)(p + 4);
        float4 a2 = *(const float4*)(p + 8);
#pragma unroll
        for (int r = 1; r < R; ++r) {
            const float* pr = p + (size_t)r * pstride;
            float4 b0 = *(const float4*)(pr);
            float4 b1 = *(const float4*)(pr + 4);
            float4 b2 = *(const float4*)(pr + 8);
            a0.x += b0.x; a0.y += b0.y; a0.z += b0.z; a0.w += b0.w;
            a1.x += b1.x; a1.y += b1.y; a1.z += b1.z; a1.w += b1.w;
            a2.x += b2.x; a2.y += b2.y; a2.z += b2.z; a2.w += b2.w;
        }
        float4 o0, o1, o2;
        psp_step(a0.x, gp, hp, gr, hr, o0.x);
        psp_step(a0.y, gp, hp, gr, hr, o0.y);
        psp_step(a0.z, gp, hp, gr, hr, o0.z);
        psp_step(a0.w, gp, hp, gr, hr, o0.w);
        psp_step(a1.x, gp, hp, gr, hr, o1.x);
        psp_step(a1.y, gp, hp, gr, hr, o1.y);
        psp_step(a1.z, gp, hp, gr, hr, o1.z);
        psp_step(a1.w, gp, hp, gr, hr, o1.w);
        psp_step(a2.x, gp, hp, gr, hr, o2.x);
        psp_step(a2.y, gp, hp, gr, hr, o2.y);
        psp_step(a2.z, gp, hp, gr, hr, o2.z);
        psp_step(a2.w, gp, hp, gr, hr, o2.w);
        float* q = sp + c * 12;
        *(float4*)(q) = o0;
        *(float4*)(q + 4) = o1;
        *(float4*)(q + 8) = o2;
    }
}

// Scan for L5 output: reads z5 in [tc][p][16] layout (p = n*4096 + f), writes f16
// spikes S16 [n][t][4096]. Wave reads are 64 lanes x 64B contiguous = 4KB segments.
__global__ void k_scan16_f16(const float* __restrict__ z, _Float16* __restrict__ s16) {
    int i = blockIdx.x * 64 + threadIdx.x;     // 16384 neurons, grid 256 x 64
    int n = i >> 12, f = i & 4095;
    const float* zp = z + (size_t)i * 16;
    _Float16* sp = s16 + ((size_t)n * TT) * 4096 + f;
    float gp = 0.f, hp = 0.f, gr = 0.f, hr = 0.f;
#define SC16_CHUNK(TCI, NTT) do {                                              \
    const float* pp = zp + (size_t)(TCI) * (16384 * 16);                       \
    float4 a0 = *(const float4*)(pp);                                          \
    float4 a1 = *(const float4*)(pp + 4);                                      \
    float4 a2 = *(const float4*)(pp + 8);                                      \
    float4 a3 = *(const float4*)(pp + 12);                                     \
    float zv[16] = {a0.x,a0.y,a0.z,a0.w,a1.x,a1.y,a1.z,a1.w,                   \
                    a2.x,a2.y,a2.z,a2.w,a3.x,a3.y,a3.z,a3.w};                  \
    _Pragma("unroll")                                                          \
    for (int tt = 0; tt < (NTT); ++tt) {                                       \
        float o;                                                               \
        psp_step(zv[tt], gp, hp, gr, hr, o);                                   \
        sp[(size_t)((TCI) * 16 + tt) * 4096] = (_Float16)o;                    \
    }                                                                          \
} while (0)
#pragma unroll 1
    for (int tcc = 0; tcc < 18; ++tcc) SC16_CHUNK(tcc, 16);
    SC16_CHUNK(18, 12);
#undef SC16_CHUNK
}

// Fused scan-pool-scan for L3 output: reads z3 [tc][p][16] (p = ((n*C+c)*H+y)*W+x),
// emits f16 spikes conv-native [n][c/8][y2][x2][t][8].
template <int C, int H2, int W2>
__global__ void __launch_bounds__(256) k_spsq16(const float* __restrict__ z,
                                                _Float16* __restrict__ s16) {
    constexpr int H = 2 * H2, W = 2 * W2;
    constexpr int NP = NBATCH * C * H * W;
    constexpr int C8 = C / 8;
    __shared__ _Float16 tile[16 * C];

    int i = blockIdx.x * 256 + threadIdx.x;    // grid exact: N*C*H2*W2*4 threads
    int q = i & 3;
    int p = i >> 2;
    int c  = p % C;
    int x2 = (p / C) % W2;
    int y2 = (p / (C * W2)) % H2;
    int n  = p / (C * W2 * H2);
    int dy = q >> 1, dx = q & 1;
    int pz = ((n * C + c) * H + 2 * y2 + dy) * W + 2 * x2 + dx;
    const float* zp = z + (size_t)pz * 16;

    int tid = threadIdx.x;
    int wt  = tid & 15;
    int wc8 = tid >> 4;
    int p0 = blockIdx.x * 64;                  // block's site (C-aligned p)
    int wx2 = (p0 / C) % W2;
    int wy2 = (p0 / (C * W2)) % H2;
    int wn  = p0 / (C * W2 * H2);
    _Float16* wbase = s16 + ((((size_t)(wn * C8 + wc8) * H2 + wy2) * W2 + wx2) * TT) * 8;

    float gp = 0.f, hp = 0.f, gr = 0.f, hr = 0.f;   // conv neuron IIR
    float Gp = 0.f, Hp = 0.f, Gr = 0.f, Hr = 0.f;   // pooled neuron IIR
#define SPSQ_CHUNK(TCI, NTT) do {                                              \
    const float* pp = zp + (size_t)(TCI) * (NP * 16);                          \
    float4 a0 = *(const float4*)(pp);                                          \
    float4 a1 = *(const float4*)(pp + 4);                                      \
    float4 a2 = *(const float4*)(pp + 8);                                      \
    float4 a3 = *(const float4*)(pp + 12);                                     \
    float zv[16] = {a0.x,a0.y,a0.z,a0.w,a1.x,a1.y,a1.z,a1.w,                   \
                    a2.x,a2.y,a2.z,a2.w,a3.x,a3.y,a3.z,a3.w};                  \
    float ov[16];                                                              \
    _Pragma("unroll")                                                          \
    for (int tt = 0; tt < (NTT); ++tt) {                                       \
        float sq;                                                              \
        psp_step(zv[tt], gp, hp, gr, hr, sq);                                  \
        float t1 = sq + __shfl_xor(sq, 1, 64);                                 \
        float pool = t1 + __shfl_xor(t1, 2, 64);                               \
        psp_step(11.0f * pool, Gp, Hp, Gr, Hr, ov[tt]);                        \
    }                                                                          \
    __syncthreads();                                                           \
    if (q == 0) {                                                              \
        _Pragma("unroll")                                                      \
        for (int tt = 0; tt < (NTT); ++tt)                                     \
            tile[tt * C + c] = (_Float16)ov[tt];                               \
    }                                                                          \
    __syncthreads();                                                           \
    if (tid < 16 * C8 && wt < (NTT)) {                                         \
        h8t v = *(const h8t*)(tile + wt * C + wc8 * 8);                        \
        *(h8t*)(wbase + (size_t)((TCI) * 16 + wt) * 8) = v;                    \
    }                                                                          \
} while (0)
#pragma unroll 1
    for (int tcc = 0; tcc < 18; ++tcc) SPSQ_CHUNK(tcc, 16);
    SPSQ_CHUNK(18, 12);
#undef SPSQ_CHUNK
}

// --- weight-pack device helpers (f16 hi/lo split: w == hi + lo * 2^-12) ---
__device__ __forceinline__ void pack_wmfma_item(int i, const float* __restrict__ w,
                                                _Float16* __restrict__ wm, int CIN, int COUT) {
    int lane = i & 63;
    int r = i >> 6;
    int ver = r & 1; r >>= 1;
    int KC = CIN >> 5, CT = COUT >> 4;
    int ct = r % CT; r /= CT;
    int kc = r % KC;
    int tap = r / KC;
    int ky = tap / 3, kx = tap % 3;
    int co  = ct * 16 + (lane & 15);
    int ci0 = kc * 32 + (lane >> 4) * 8;
    _Float16 out[8];
#pragma unroll
    for (int j = 0; j < 8; ++j) {
        float wf = w[((co * CIN + ci0 + j) * 3 + ky) * 3 + kx];
        _Float16 hi = (_Float16)wf;
        out[j] = ver ? (_Float16)((wf - (float)hi) * 4096.0f) : hi;
    }
    *(h8t*)(wm + (size_t)i * 8) = *(h8t*)out;
}

__device__ __forceinline__ void pack_wfc_item(int i, const float* __restrict__ w,
                                              _Float16* __restrict__ wm, int FIN, int COUT) {
    int lane = i & 63;
    int r = i >> 6;
    int ver = r & 1; r >>= 1;
    int CT = COUT >> 4;
    int ct = r % CT;
    int kg = r / CT;
    int co = ct * 16 + (lane & 15);
    int f0 = kg * 32 + (lane >> 4) * 8;
    _Float16 out[8];
#pragma unroll
    for (int j = 0; j < 8; ++j) {
        float wf = w[(size_t)co * FIN + f0 + j];
        _Float16 hi = (_Float16)wf;
        out[j] = ver ? (_Float16)((wf - (float)hi) * 4096.0f) : hi;
    }
    *(h8t*)(wm + (size_t)i * 8) = *(h8t*)out;
}

__device__ __forceinline__ void pack_wl1_item(int i, const float* __restrict__ w,
                                              _Float16* __restrict__ wm) {
    int lane = i & 63;
    int r = i >> 6;
    int ver = r & 1;
    int ch = (r >> 1) & 1;
    int kc = r >> 2;
    int co = ch * 16 + (lane & 15);
    int k0 = kc * 32 + (lane >> 4) * 8;
    _Float16 out[8];
#pragma unroll
    for (int j = 0; j < 8; ++j) {
        int k = k0 + j;
        int ky = k >> 4, slot = k & 15, kx = slot >> 1, ci = slot & 1;
        float wf = (ky < 5 && kx < 5) ? w[((co * 2 + ci) * 5 + ky) * 5 + kx] : 0.f;
        _Float16 hif = (_Float16)wf;
        out[j] = ver ? (_Float16)((wf - (float)hif) * 4096.0f) : hif;
    }
    *(h8t*)(wm + (size_t)i * 8) = *(h8t*)out;
}

// All 4 weight packs in ONE launch (saves 3 launch gaps; total 276,736 items).
__global__ void k_pack_all(const float* __restrict__ w1, const float* __restrict__ w2,
                           const float* __restrict__ w3, const float* __restrict__ w4a,
                           _Float16* __restrict__ wl1m, _Float16* __restrict__ wm2,
                           _Float16* __restrict__ wm3, _Float16* __restrict__ wm4) {
    int i = blockIdx.x * 256 + threadIdx.x;
    if (i < 768)          pack_wl1_item(i, w1, wl1m);
    else if (i < 5376)    pack_wmfma_item(i - 768, w2, wm2, 32, 64);
    else if (i < 14592)   pack_wmfma_item(i - 5376, w3, wm3, 64, 64);
    else if (i < 276736)  pack_wfc_item(i - 14592, w4a, wm4, 4096, 256);
}

// 4x4 sum-pool * 11.0 over (N,2,128,128,T) -> z (N,2,32,32,T). Thread = (p, tc), tc fastest.
__global__ void k_pool4(const float* __restrict__ x, float* __restrict__ z) {
    int idx = blockIdx.x * 256 + threadIdx.x;
    if (idx >= NBATCH * 2 * 32 * 32 * TC) return;
    int tc = idx % TC;
    int p  = idx / TC;
    int w  = p % 32;
    int h  = (p / 32) % 32;
    int nc = p / (32 * 32);
    const float* base = x + (((size_t)nc * 128 + h * 4) * 128 + w * 4) * TT + tc * 4;
    float ax = 0.f, ay = 0.f, az = 0.f, aw = 0.f;
#pragma unroll
    for (int i = 0; i < 4; ++i)
#pragma unroll
        for (int j = 0; j < 4; ++j) {
            float4 v = *(const float4*)(base + ((size_t)i * 128 + j) * TT);
            ax += v.x; ay += v.y; az += v.z; aw += v.w;
        }
    float4 o; o.x = 11.0f * ax; o.y = 11.0f * ay; o.z = 11.0f * az; o.w = 11.0f * aw;
    *(float4*)(z + (size_t)p * TT + tc * 4) = o;
}

// Fused L1 (v3): 5x5 conv (2->32) MFMA + psp + 2x2 pool + psp -> s2h f16 conv-native.
// Block = (n, ch co-half, xh x-octet, y2 pool-row) owns ALL 300 t (IIR in VGPRs).
// v3 vs v2: T-TILE 32 (was 16) — barrier count 57 -> 30; the grid is neuron-capped
// at 512 blocks (2/CU) so L1 cannot win occupancy, only amortize phase stalls.
// LDS 56.7 KB (2 blocks/CU kept). Per-thread stage geometry simplifies at tile 32:
// item row r == item index ii (i>>8), (tq,lx,ci) identical across ii.
// Numerics: identical values and op order -> absmax unchanged (0.0).
__global__ void __launch_bounds__(256, 2) k_l1_fused(const float* __restrict__ s0,
                                                     const _Float16* __restrict__ wl1,
                                                     _Float16* __restrict__ s2h) {
    constexpr int NT = 10;                    // ceil(300/32); tile 9 has 12 valid t
    __shared__ _Float16 stage[7 * 32 * 42];   // [row7][t32][42: 16lx x 2ci + pad] 18816B
    __shared__ float    trans[256 * 33];      // [neuron 256][32 t + 1 pad]      33792B
    __shared__ _Float16 tile[4 * 32 * 16];    // [x2l][t32][co]                   4096B

    int bid = blockIdx.x;                     // grid 512 = n4 * ch2 * xh4 * y2_16
    int y2 = bid & 15;
    int xh = (bid >> 4) & 3;
    int ch = (bid >> 6) & 1;
    int n  = bid >> 7;
    int tid = threadIdx.x;
    int lane = tid & 63;
    int wv = tid >> 6;          // 4 waves: (yy, xq)
    int tl = lane & 15;
    int hi = lane >> 4;
    int yy = wv >> 1;
    int xq = wv & 1;

    int q     = tid & 3;        // scan role: dy=q>>1, dx=q&1 (lane bits 0-1 -> shfl pool)
    int co_s  = (tid >> 2) & 15;
    int x2l_s = tid >> 6;
    int wt  = tid & 31;         // writer role: all 256 threads (4wx x 2wc8 x 32t)
    int wc8 = (tid >> 5) & 1;
    int wx  = tid >> 6;

    // stage geometry: thread handles (tq = tid&7, lx, ci) for ALL 7 rows (r = ii).
    int tq = tid & 7;
    int lx = (tid >> 3) & 15;
    int ci = tid >> 7;
    int gx = xh * 8 + lx - 2;
    bool gxok = (gx >= 0 && gx < 32);
    size_t boff = (((size_t)(n * 2 + ci) * 32) * 32 + (gxok ? gx : 0)) * TT + tq * 4;  // gy=0
    int adr0 = (tq * 4) * 42 + lx * 2 + ci;

    const h8t* wv4 = (const h8t*)wl1;
    h8t wfr[3][2];
#pragma unroll
    for (int kc = 0; kc < 3; ++kc) {
        wfr[kc][0] = wv4[((kc * 2 + ch) * 2 + 0) * 64 + lane];
        wfr[kc][1] = wv4[((kc * 2 + ch) * 2 + 1) * 64 + lane];
    }

    float gp = 0.f, hp = 0.f, gr = 0.f, hr = 0.f;
    float Gp = 0.f, Hp = 0.f, Gr = 0.f, Hr = 0.f;

    // prologue prefetch: tile 0 (t 0..31, all < 300)
    float4 pf[7];
#pragma unroll
    for (int ii = 0; ii < 7; ++ii) {
        int gy = y2 * 2 + ii - 2;
        pf[ii] = make_float4(0.f, 0.f, 0.f, 0.f);
        if (gxok && gy >= 0 && gy < 32)
            pf[ii] = *(const float4*)(s0 + boff + (size_t)gy * (32 * TT));
    }

#pragma unroll 1
    for (int tc = 0; tc < NT; ++tc) {
        // stage write from prefetched regs (f32 -> f16)
#pragma unroll
        for (int ii = 0; ii < 7; ++ii) {
            int a = adr0 + ii * (32 * 42);
            stage[a + 0 * 42] = (_Float16)pf[ii].x;
            stage[a + 1 * 42] = (_Float16)pf[ii].y;
            stage[a + 2 * 42] = (_Float16)pf[ii].z;
            stage[a + 3 * 42] = (_Float16)pf[ii].w;
        }
        // issue next tile's loads now — in flight across MFMA + scan phases
        if (tc + 1 < NT) {
#pragma unroll
            for (int ii = 0; ii < 7; ++ii) {
                int gy = y2 * 2 + ii - 2;
                float4 v = make_float4(0.f, 0.f, 0.f, 0.f);
                if (gxok && gy >= 0 && gy < 32 && (tc + 1) * 32 + tq * 4 + 3 < TT)
                    v = *(const float4*)(s0 + boff + (size_t)gy * (32 * TT) + (tc + 1) * 32);
                pf[ii] = v;
            }
        }
        __syncthreads();   // [B] stage ready
        // MFMA: wave (yy,xq) -> 16 co x 8 xo-halves x 32 t (two 16-t groups).
        f32x4 ah4[2][4], al4[2][4];
#pragma unroll
        for (int tg = 0; tg < 2; ++tg)
#pragma unroll
            for (int xi = 0; xi < 4; ++xi) {
                ah4[tg][xi] = (f32x4){0.f, 0.f, 0.f, 0.f};
                al4[tg][xi] = (f32x4){0.f, 0.f, 0.f, 0.f};
            }
#pragma unroll
        for (int kc = 0; kc < 3; ++kc) {
            int rowb = yy + 2 * kc + (hi >> 1);
#pragma unroll
            for (int tg = 0; tg < 2; ++tg) {
#pragma unroll
                for (int xi = 0; xi < 4; ++xi) {
                    int xo = xq * 4 + xi;
                    const uint32_t* lp = (const uint32_t*)(stage + (rowb * 32 + tg * 16 + tl) * 42 + xo * 2 + (hi & 1) * 8);
                    union { uint32_t u[4]; h8t h; } bu;
                    bu.u[0] = lp[0]; bu.u[1] = lp[1]; bu.u[2] = lp[2]; bu.u[3] = lp[3];
                    ah4[tg][xi] = __builtin_amdgcn_mfma_f32_16x16x32_f16(wfr[kc][0], bu.h, ah4[tg][xi], 0, 0, 0);
                    al4[tg][xi] = __builtin_amdgcn_mfma_f32_16x16x32_f16(wfr[kc][1], bu.h, al4[tg][xi], 0, 0, 0);
                }
            }
        }
        // transpose -> trans[neuron][t]; neuron = (x2l*16+co)*4 + dy*2 + dx.
#pragma unroll
        for (int tg = 0; tg < 2; ++tg)
#pragma unroll
            for (int xi = 0; xi < 4; ++xi) {
                int xo = xq * 4 + xi;
#pragma unroll
                for (int r = 0; r < 4; ++r) {
                    float u = ah4[tg][xi][r] + al4[tg][xi][r] * 2.44140625e-4f;
                    int rowt = ((xo >> 1) * 16 + hi * 4 + r) * 4 + yy * 2 + (xo & 1);
                    trans[rowt * 33 + tg * 16 + tl] = u;
                }
            }
        __syncthreads();   // [C] trans ready
        // scan: each thread = 1 conv neuron; quad (lane bits 0-1) pools via shfl.
        // t >= 300 slots are zero-staged -> harmless trailing decay (after all output).
#pragma unroll
        for (int t = 0; t < 32; ++t) {
            float u = trans[tid * 33 + t];
            float sq;
            psp_step(u, gp, hp, gr, hr, sq);
            float t1 = sq + __shfl_xor(sq, 1, 64);
            float pool = t1 + __shfl_xor(t1, 2, 64);
            float ov;
            psp_step(11.0f * pool, Gp, Hp, Gr, Hr, ov);
            if (q == 0) tile[(x2l_s * 32 + t) * 16 + co_s] = (_Float16)ov;
        }
        __syncthreads();   // [D] tile ready
        // write pooled spikes: [n][cg8 4][y2 16][x2 16][t 300][8]
        {
            int tg = tc * 32 + wt;
            if (tg < TT) {
                h8t v = *(const h8t*)(tile + (wx * 32 + wt) * 16 + wc8 * 8);
                int cg8 = ch * 2 + wc8;
                int x2g = xh * 4 + wx;
                *(h8t*)(s2h + ((((size_t)(n * 4 + cg8) * 16 + y2) * 16 + x2g) * (size_t)TT + tg) * 8) = v;
            }
        }
    }
}

// MFMA 3x3 conv (pad 1). Input: f16 spikes [n][ci/8][y][x][t][8]. Output z in
// [tc][p][16] layout. XSPL x-split doubles the grid for occupancy; launch_bounds
// (256,2) — round-4's (256,4) forced 64-VGPR acc spill. With XSPL=2 the acc block
// halves so the HW reaches ~4 blocks/CU via LDS/VGPR limits naturally.
template <int CIN, int COUT, int H, int W, int YPB, int XSPL>
__global__ void __launch_bounds__(256, 2) k_conv_mfma(const _Float16* __restrict__ s16,
                                                      const _Float16* __restrict__ wm,
                                                      float* __restrict__ z) {
    constexpr int NT = 19;          // ceil(300/16)
    constexpr int KC = CIN / 32;
    constexpr int CH = CIN / 8;
    constexpr int XW = W / XSPL;    // output x per block (even -> line ownership kept)
    constexpr int XL = XW + 2;
    constexpr int CT = COUT / 16;
    constexpr int XPW = XW / 4;
    constexpr int ROWS = YPB + 2;
    constexpr int NP = NBATCH * COUT * H * W;
    __shared__ _Float16 lds[ROWS * XL * 16 * CIN];

    int bid = blockIdx.x;
    int tc = bid % NT;
    int r0 = bid / NT;
    int yb = (r0 % (H / YPB)) * YPB;
    r0 /= (H / YPB);
    int xh = r0 % XSPL;
    int n  = r0 / XSPL;
    int xb = xh * XW;
    int tid = threadIdx.x;

    constexpr int TOT = ROWS * XL * CH * 16;
    for (int i = tid; i < TOT; i += 256) {
        int t   = i & 15;
        int c   = (i >> 4) % CH;
        int xc  = ((i >> 4) / CH) % XL;
        int row = ((i >> 4) / CH) / XL;
        int tg = tc * 16 + t;
        int xi = xb + xc - 1;
        int yi = yb + row - 1;
        h8t v;
#pragma unroll
        for (int e = 0; e < 8; ++e) v[e] = (_Float16)0.0f;
        if (xi >= 0 && xi < W && yi >= 0 && yi < H && tg < TT)
            v = *(const h8t*)(s16 + ((((size_t)(n * CH + c) * H + yi) * W + xi) * TT + tg) * 8);
        int swz = (CIN == 32) ? ((t >> 1) & 3) : (t & 7);
        int off = ((row * XL + xc) * 16 + t) * CIN + ((c ^ swz) << 3);
        *(h8t*)(lds + off) = v;
    }
    __syncthreads();

    int lane = tid & 63;
    int wv   = tid >> 6;
    int tl   = lane & 15;
    int hi   = lane >> 4;
    const h8t* wmv = (const h8t*)wm;
    int swz = (CIN == 32) ? ((tl >> 1) & 3) : (tl & 7);

#pragma unroll
    for (int yy = 0; yy < YPB; ++yy) {
        f32x4 acc_h[XPW][CT], acc_l[XPW][CT];
#pragma unroll
        for (int a = 0; a < XPW; ++a)
#pragma unroll
            for (int b = 0; b < CT; ++b) {
                acc_h[a][b] = (f32x4){0.f, 0.f, 0.f, 0.f};
                acc_l[a][b] = (f32x4){0.f, 0.f, 0.f, 0.f};
            }
#pragma unroll
        for (int ky = 0; ky < 3; ++ky) {
#pragma unroll
            for (int kx = 0; kx < 3; ++kx) {
                int tap = ky * 3 + kx;
#pragma unroll
                for (int kc = 0; kc < KC; ++kc) {
                    h8t bf[XPW];
#pragma unroll
                    for (int xi = 0; xi < XPW; ++xi) {
                        int x = wv * XPW + xi;
                        int c = kc * 4 + hi;
                        int off = (((yy + ky) * XL + (x + kx)) * 16 + tl) * CIN + ((c ^ swz) << 3);
                        bf[xi] = *(const h8t*)(lds + off);
                    }
#pragma unroll
                    for (int ct = 0; ct < CT; ++ct) {
                        size_t wbase = ((size_t)(tap * KC + kc) * CT + ct) * 2;
                        h8t ah = wmv[(wbase + 0) * 64 + lane];
                        h8t al = wmv[(wbase + 1) * 64 + lane];
#pragma unroll
                        for (int xi = 0; xi < XPW; ++xi) {
                            acc_h[xi][ct] = __builtin_amdgcn_mfma_f32_16x16x32_f16(ah, bf[xi], acc_h[xi][ct], 0, 0, 0);
                            acc_l[xi][ct] = __builtin_amdgcn_mfma_f32_16x16x32_f16(al, bf[xi], acc_l[xi][ct], 0, 0, 0);
                        }
                    }
                }
            }
        }
        // C/D layout: col = lane&15 (= t), row = (lane>>4)*4 + r (= cout)
#pragma unroll
        for (int xi = 0; xi < XPW; ++xi) {
            int x = xb + wv * XPW + xi;
#pragma unroll
            for (int ct = 0; ct < CT; ++ct) {
#pragma unroll
                for (int r = 0; r < 4; ++r) {
                    int co = ct * 16 + hi * 4 + r;
                    int pz = ((n * COUT + co) * H + (yb + yy)) * W + x;
                    z[((size_t)tc * NP + pz) * 16 + tl]
                        = acc_h[xi][ct][r] + acc_l[xi][ct][r] * 2.44140625e-4f;
                }
            }
        }
    }
}

// MFMA FC: out[n][co][t] = sum_f w[co][f] * s16[n][t][f]. Output z6 [n][co][300] f32.
template <int FIN, int OUT>
__global__ void __launch_bounds__(256) k_fc_mfma(const _Float16* __restrict__ s16,
                                                 const _Float16* __restrict__ wm,
                                                 float* __restrict__ z) {
    constexpr int NT = 19;
    constexpr int CT = OUT / 16;
    constexpr int KCH = 512;
    constexpr int NK = FIN / KCH;
    __shared__ _Float16 lds[KCH * 16];   // 16 KB

    int bid = blockIdx.x;           // grid = (CT/4) * NBATCH * NT
    int tc = bid % NT;
    int n  = (bid / NT) % NBATCH;
    int cg = bid / (NT * NBATCH);
    int tid = threadIdx.x;
    int lane = tid & 63, wv = tid >> 6;
    int tl = lane & 15, hi = lane >> 4;
    int ct = cg * 4 + wv;

    f32x4 acc_h = (f32x4){0.f, 0.f, 0.f, 0.f};
    f32x4 acc_l = (f32x4){0.f, 0.f, 0.f, 0.f};
    const h8t* wmv = (const h8t*)wm;

    for (int kb = 0; kb < NK; ++kb) {
        __syncthreads();
#pragma unroll
        for (int j = 0; j < 4; ++j) {
            int chunk = tid + j * 256;
            int c = chunk & 63;
            int t = chunk >> 6;
            int tg = tc * 16 + t;
            h8t v;
#pragma unroll
            for (int e = 0; e < 8; ++e) v[e] = (_Float16)0.0f;
            if (tg < TT) v = *(const h8t*)(s16 + ((size_t)(n * TT + tg) * FIN + kb * KCH + c * 8));
            *(h8t*)(lds + ((t * 64 + (c ^ (t & 7))) << 3)) = v;
        }
        __syncthreads();
#pragma unroll
        for (int kc = 0; kc < KCH / 32; ++kc) {
            int c = kc * 4 + hi;
            h8t bf = *(const h8t*)(lds + ((tl * 64 + (c ^ (tl & 7))) << 3));
            size_t wbase = ((size_t)((kb * (KCH / 32) + kc) * CT + ct)) * 2;
            h8t ah = wmv[(wbase + 0) * 64 + lane];
            h8t al = wmv[(wbase + 1) * 64 + lane];
            acc_h = __builtin_amdgcn_mfma_f32_16x16x32_f16(ah, bf, acc_h, 0, 0, 0);
            acc_l = __builtin_amdgcn_mfma_f32_16x16x32_f16(al, bf, acc_l, 0, 0, 0);
        }
    }
    int tg = tc * 16 + tl;
    if (tg < TT) {
#pragma unroll
        for (int r = 0; r < 4; ++r) {
            int co = ct * 16 + hi * 4 + r;
            z[(size_t)(n * OUT + co) * TT + tg] = acc_h[r] + acc_l[r] * 2.44140625e-4f;
        }
    }
}

// FC with packed fp32 FMA over the t dimension (tiny L7 11x256).
template <int OUT, int FIN, int OPER, int FSPLIT>
__global__ void k_fc_a(const float* __restrict__ s, const float* __restrict__ wgt,
                       float* __restrict__ z) {
    constexpr int OG = OUT / OPER, FCH = FIN / FSPLIT;
    int idx = blockIdx.x * 256 + threadIdx.x;
    if (idx >= NBATCH * OG * TC * FSPLIT) return;
    int tc = idx % TC;
    int og = (idx / TC) % OG;
    int n  = (idx / (TC * OG)) % NBATCH;
    int sp = idx / (TC * OG * NBATCH);
    const float* sb = s + (size_t)n * FIN * TT + (size_t)sp * FCH * TT + tc * 4;
    const float* wb = wgt + (size_t)sp * FCH;
    pf2 acc[OPER][2];
#pragma unroll
    for (int k = 0; k < OPER; ++k) { acc[k][0] = (pf2){0.f, 0.f}; acc[k][1] = (pf2){0.f, 0.f}; }
#pragma unroll 2
    for (int f = 0; f < FCH; f += 4) {
        float4 s0 = *(const float4*)(sb + (size_t)(f + 0) * TT);
        float4 s1 = *(const float4*)(sb + (size_t)(f + 1) * TT);
        float4 s2 = *(const float4*)(sb + (size_t)(f + 2) * TT);
        float4 s3 = *(const float4*)(sb + (size_t)(f + 3) * TT);
        pf2 s0a = {s0.x, s0.y}, s0b = {s0.z, s0.w};
        pf2 s1a = {s1.x, s1.y}, s1b = {s1.z, s1.w};
        pf2 s2a = {s2.x, s2.y}, s2b = {s2.z, s2.w};
        pf2 s3a = {s3.x, s3.y}, s3b = {s3.z, s3.w};
#pragma unroll
        for (int k = 0; k < OPER; ++k) {
            float4 wv = *(const float4*)(wb + (size_t)(og * OPER + k) * FIN + f);
            pf2 wx = {wv.x, wv.x}, wy = {wv.y, wv.y}, wz = {wv.z, wv.z}, ww = {wv.w, wv.w};
            pf2 a0 = acc[k][0], a1 = acc[k][1];
            a0 = __builtin_elementwise_fma(wx, s0a, a0);
            a0 = __builtin_elementwise_fma(wy, s1a, a0);
            a0 = __builtin_elementwise_fma(wz, s2a, a0);
            a0 = __builtin_elementwise_fma(ww, s3a, a0);
            a1 = __builtin_elementwise_fma(wx, s0b, a1);
            a1 = __builtin_elementwise_fma(wy, s1b, a1);
            a1 = __builtin_elementwise_fma(wz, s2b, a1);
            a1 = __builtin_elementwise_fma(ww, s3b, a1);
            acc[k][0] = a0; acc[k][1] = a1;
        }
    }
#pragma unroll
    for (int k = 0; k < OPER; ++k) {
        float4 o;
        o.x = acc[k][0].x; o.y = acc[k][0].y; o.z = acc[k][1].x; o.w = acc[k][1].y;
        *(float4*)(z + ((size_t)sp * NBATCH * OUT + (size_t)n * OUT + og * OPER + k) * TT + tc * 4) = o;
    }
}

extern "C" void kernel_launch(void* const* d_in, const int* in_sizes, int n_in,
                              void* d_out, int out_size, void* d_ws, size_t ws_size,
                              hipStream_t stream) {
    const float* s_in = (const float*)d_in[0]; // (4,2,128,128,300)
    const float* w1   = (const float*)d_in[1]; // (32,2,5,5)
    const float* w2   = (const float*)d_in[2]; // (64,32,3,3)
    const float* w3   = (const float*)d_in[3]; // (64,64,3,3)
    const float* w4a  = (const float*)d_in[4]; // (256,4096)
    const float* w4b  = (const float*)d_in[5]; // (11,256)
    float* out = (float*)d_out;                // (4,11,300)

    // Workspace map (floats): Z 39,321,600 | Sb 9,830,400 | WP 56,896.
    // Z: z3 [tc][65536][16] = 19.92M floats at [0..); z5 [tc][16384][16] = 4.98M;
    //    S16 @ Z+25M (2.46M f); wm4 @ Z+28M (1.05M f); wl1m @ Z+30M.
    // Sb: s0 f32 [0..2.46M); s2h f16 @ Sb+2.5M; s4h f16 @ Sb+5M (sequential liveness);
    //     s6 f32 reuses Sb[0..).
    float* Z  = (float*)d_ws;
    float* Sb = Z + 39321600;
    float* WP = Sb + 9830400;
    _Float16* wm2 = (_Float16*)(WP + 1600);
    _Float16* wm3 = (_Float16*)(WP + 1600 + 18432);
    _Float16* S16 = (_Float16*)(Z + 25000000);
    _Float16* wm4 = (_Float16*)(Z + 28000000);
    _Float16* wl1m = (_Float16*)(Z + 30000000);          // 6144 halves
    float* s0 = Sb;                                      // f32 (4,2,32,32,300)
    _Float16* s2h = (_Float16*)(Sb + 2500000);           // f16 [n][4][16][16][300][8]
    _Float16* s4h = (_Float16*)(Sb + 5000000);           // f16 [n][8][8][8][300][8]

    auto g = [](int n) { return (n + 255) / 256; };
    auto g64 = [](int n) { return (n + 63) / 64; };

    // all weight packs in one launch (independent of activations)
    k_pack_all<<<g(276736), 256, 0, stream>>>(w1, w2, w3, w4a, wl1m, wm2, wm3, wm4);

    // L0: 4x4 pool + psp -> s0 (4,2,32,32,300) f32 @ Sb
    k_pool4<<<g(614400), 256, 0, stream>>>(s_in, Z);
    k_scan_redp<1><<<g64(8192), 64, 0, stream>>>(Z, s0, 8192, 0);

    // L1 fused v3 (32-t tiles): conv 5x5 MFMA + psp + pool + psp -> s2h. grid 512.
    k_l1_fused<<<512, 256, 0, stream>>>(s0, wl1m, s2h);

    // L3 conv 3x3 (32->64, 16x16) MFMA, YPB=2 XSPL=2: z3 [tc][p][16] @ Z. grid 1216.
    k_conv_mfma<32, 64, 16, 16, 2, 2><<<1216, 256, 0, stream>>>(s2h, wm2, Z);
    // L3 psp + 2x2 pool + L4 psp -> s4h f16 conv-native. 256 blocks.
    k_spsq16<64, 8, 8><<<256, 256, 0, stream>>>(Z, s4h);

    // L5 conv 3x3 (64->64, 8x8) MFMA, YPB=1 XSPL=2: z5 [tc][p][16] @ Z. grid 1216.
    k_conv_mfma<64, 64, 8, 8, 1, 2><<<1216, 256, 0, stream>>>(s4h, wm3, Z);
    // psp scan -> f16 spikes [n][t][f] @ S16 (16384 neurons).
    k_scan16_f16<<<256, 64, 0, stream>>>(Z, S16);

    // L6: fc 4096->256 MFMA: z6 (4,256,300) @ Z. grid = 4 cog * 4 n * 19 tc = 304.
    k_fc_mfma<4096, 256><<<304, 256, 0, stream>>>(S16, wm4, Z);
    k_scan_redp<1><<<g64(1024), 64, 0, stream>>>(Z, Sb, 1024, 0);

    // L7: fc 256->11 + psp -> out
    k_fc_a<11, 256, 1, 1><<<g(3300), 256, 0, stream>>>(Sb, w4b, Z);
    k_scan_redp<1><<<1, 64, 0, stream>>>(Z, out, 44, 0);
}